// Round 13
// baseline (559.719 us; speedup 1.0000x reference)
//
#include <hip/hip_runtime.h>
#include <hip/hip_bf16.h>
#include <stdint.h>

// Problem constants (MultiScaleRetention: B=2, N=4096, D_MODEL=2048, H=4)
constexpr int Bb   = 2;
constexpr int Nn   = 4096;
constexpr int DM   = 2048;
constexpr int Hh   = 4;
constexpr int DK   = 256;    // KEY_DIM / H
constexpr int DV   = 512;    // D_MODEL / H
constexpr int QKS  = 2048;   // fused q|k row stride (q cols 0-1023, k cols 1024-2047)
constexpr int CH   = 64;     // chunk
constexpr int NC   = Nn / CH;   // 64 chunks
constexpr int M    = Bb * Nn;   // 8192 rows

typedef __attribute__((ext_vector_type(8))) short s16x8;   // 8 bf16 (4 VGPRs)
typedef __attribute__((ext_vector_type(4))) float f32x4;

__device__ __forceinline__ float b2f(uint16_t h) {
  return __uint_as_float(((uint32_t)h) << 16);
}
__device__ __forceinline__ uint16_t f2b(float f) {   // RNE, finite inputs
  uint32_t u = __float_as_uint(f);
  return (uint16_t)((u + 0x7fffu + ((u >> 16) & 1u)) >> 16);
}

// async global->LDS, 16B per lane; LDS dest = wave-uniform base + lane*16
__device__ __forceinline__ void gload16(const void* g, void* l) {
  __builtin_amdgcn_global_load_lds(
      (const __attribute__((address_space(1))) void*)g,
      (__attribute__((address_space(3))) void*)l, 16, 0, 0);
}

#define BARRIER()  asm volatile("s_barrier" ::: "memory")
#define WAITLGKM() do { asm volatile("s_waitcnt lgkmcnt(0)" ::: "memory"); \
                        __builtin_amdgcn_sched_barrier(0); } while (0)
#define VMCNT6()   asm volatile("s_waitcnt vmcnt(6)" ::: "memory")
#define VMCNT4()   asm volatile("s_waitcnt vmcnt(4)" ::: "memory")
#define VMCNT3()   asm volatile("s_waitcnt vmcnt(3)" ::: "memory")
#define VMCNT0()   asm volatile("s_waitcnt vmcnt(0)" ::: "memory")

// ---------------------------------------------------------------------------
// fp32 -> bf16 bulk convert, 8 elems/thread
// ---------------------------------------------------------------------------
__global__ __launch_bounds__(256) void conv_f2b(const float* __restrict__ s,
                                                uint16_t* __restrict__ d, int n8) {
  int i = blockIdx.x * 256 + threadIdx.x;
  if (i >= n8) return;
  const float4* sp = (const float4*)s;
  float4 a = sp[2 * i], b = sp[2 * i + 1];
  uint4 o;
  o.x = (uint32_t)f2b(a.x) | ((uint32_t)f2b(a.y) << 16);
  o.y = (uint32_t)f2b(a.z) | ((uint32_t)f2b(a.w) << 16);
  o.z = (uint32_t)f2b(b.x) | ((uint32_t)f2b(b.y) << 16);
  o.w = (uint32_t)f2b(b.z) | ((uint32_t)f2b(b.w) << 16);
  ((uint4*)d)[i] = o;
}

// ---------------------------------------------------------------------------
// fused Wq/Wk/Wv/Wg fp32->bf16 into stacked [6144][2048] bf16. 8 elems/thread.
// ---------------------------------------------------------------------------
__global__ __launch_bounds__(256) void conv_w4(const float* __restrict__ Wq,
                                               const float* __restrict__ Wk,
                                               const float* __restrict__ Wv,
                                               const float* __restrict__ Wg,
                                               uint16_t* __restrict__ dst) {
  const int i = blockIdx.x * 256 + threadIdx.x;   // < 1572864
  const float* s; int off;
  if (i < 262144)       { s = Wq; off = i; }
  else if (i < 524288)  { s = Wk; off = i - 262144; }
  else if (i < 1048576) { s = Wv; off = i - 524288; }
  else                  { s = Wg; off = i - 1048576; }
  const float4* sp = (const float4*)s;
  float4 a = sp[2 * off], b = sp[2 * off + 1];
  uint4 o;
  o.x = (uint32_t)f2b(a.x) | ((uint32_t)f2b(a.y) << 16);
  o.y = (uint32_t)f2b(a.z) | ((uint32_t)f2b(a.w) << 16);
  o.z = (uint32_t)f2b(b.x) | ((uint32_t)f2b(b.y) << 16);
  o.w = (uint32_t)f2b(b.z) | ((uint32_t)f2b(b.w) << 16);
  ((uint4*)dst)[i] = o;
}

// ---------------------------------------------------------------------------
// Fused phase-1 GEMM, 8-PHASE template (round-12 proven: 217us, MfmaUtil 42%,
// bank conflicts 0, absmax bit-exact). Unchanged this round.
// ---------------------------------------------------------------------------
__global__ __launch_bounds__(512) void gemm_fused3(const uint16_t* __restrict__ A,
                                                   const uint16_t* __restrict__ W,
                                                   uint16_t* __restrict__ out0,
                                                   int K) {
  __shared__ uint16_t Al[2][2][8192];   // [slot][khalf][256*32]
  __shared__ uint16_t Bl[2][2][8192];
  const int tid = threadIdx.x;
  const int l = tid & 63, w = tid >> 6;
  const int wm = w >> 2, wn = w & 3;
  const int m0 = blockIdx.x * 256, n0 = blockIdx.y * 256;
  const int fr = l & 15;
  const int pu = (((l >> 4) ^ ((fr >> 1) & 3)) * 8);
  const int ssw = ((l & 3) ^ ((l >> 3) & 3)) * 8;
  const uint16_t* aS = A + (size_t)(m0 + w * 32 + (l >> 2)) * K + ssw;
  const uint16_t* wS = W + (size_t)(n0 + w * 32 + (l >> 2)) * K + ssw;

  f32x4 acc[8][4];
#pragma unroll
  for (int mi = 0; mi < 8; ++mi)
#pragma unroll
    for (int nj = 0; nj < 4; ++nj) {
      f32x4 z = {0.f, 0.f, 0.f, 0.f};
      acc[mi][nj] = z;
    }

#define STG_A(S, KH, KT) do {                                                \
    const uint16_t* _p = aS + (size_t)(KT) * 64 + (KH) * 32;                 \
    gload16(_p,                   &Al[S][KH][(w * 32) * 32]);                \
    gload16(_p + (size_t)16 * K,  &Al[S][KH][(w * 32 + 16) * 32]);           \
  } while (0)
#define STG_B(S, KH, KT) do {                                                \
    const uint16_t* _p = wS + (size_t)(KT) * 64 + (KH) * 32;                 \
    gload16(_p,                   &Bl[S][KH][(w * 32) * 32]);                \
    gload16(_p + (size_t)16 * K,  &Bl[S][KH][(w * 32 + 16) * 32]);           \
  } while (0)
#define LDA(S, KH, MI) (*(const s16x8*)&Al[S][KH][(wm * 128 + (MI) * 16 + fr) * 32 + pu])
#define LDB(S, KH, NJ) (*(const s16x8*)&Bl[S][KH][(wn * 64 + (NJ) * 16 + fr) * 32 + pu])
#define MFMA16(Q) do {                                                       \
    __builtin_amdgcn_s_setprio(1);                                           \
    _Pragma("unroll")                                                        \
    for (int mi = 0; mi < 8; ++mi)                                           \
      acc[mi][2*(Q)] = __builtin_amdgcn_mfma_f32_16x16x32_bf16(              \
          aF[mi], bF0, acc[mi][2*(Q)], 0, 0, 0);                             \
    _Pragma("unroll")                                                        \
    for (int mi = 0; mi < 8; ++mi)                                           \
      acc[mi][2*(Q)+1] = __builtin_amdgcn_mfma_f32_16x16x32_bf16(            \
          aF[mi], bF1, acc[mi][2*(Q)+1], 0, 0, 0);                           \
    __builtin_amdgcn_s_setprio(0);                                           \
  } while (0)

  STG_A(0, 0, 0); STG_B(0, 0, 0); STG_A(0, 1, 0); STG_B(0, 1, 0);
  STG_A(1, 0, 1); STG_B(1, 0, 1);
  VMCNT0();
  BARRIER();

  const int NI = K / 128;
  s16x8 aF[8], bF0, bF1;

  for (int i = 0; i < NI; ++i) {
    const bool nl = (i < NI - 1);
    const size_t t1 = 2 * i + 1, t2 = 2 * i + 2, t3 = 2 * i + 3;
#pragma unroll
    for (int mi = 0; mi < 8; ++mi) aF[mi] = LDA(0, 0, mi);
    bF0 = LDB(0, 0, 0); bF1 = LDB(0, 0, 1);
    STG_A(1, 1, t1);
    BARRIER(); WAITLGKM(); MFMA16(0); BARRIER();
    bF0 = LDB(0, 0, 2); bF1 = LDB(0, 0, 3);
    STG_B(1, 1, t1);
    BARRIER(); WAITLGKM(); MFMA16(1); BARRIER();
#pragma unroll
    for (int mi = 0; mi < 8; ++mi) aF[mi] = LDA(0, 1, mi);
    bF0 = LDB(0, 1, 0); bF1 = LDB(0, 1, 1);
    if (nl) STG_A(0, 0, t2);
    BARRIER(); WAITLGKM(); MFMA16(0); BARRIER();
    bF0 = LDB(0, 1, 2); bF1 = LDB(0, 1, 3);
    if (nl) STG_B(0, 0, t2);
    BARRIER(); WAITLGKM(); MFMA16(1);
    if (nl) VMCNT4(); else VMCNT0();
    BARRIER();
#pragma unroll
    for (int mi = 0; mi < 8; ++mi) aF[mi] = LDA(1, 0, mi);
    bF0 = LDB(1, 0, 0); bF1 = LDB(1, 0, 1);
    if (nl) STG_A(0, 1, t2);
    BARRIER(); WAITLGKM(); MFMA16(0); BARRIER();
    bF0 = LDB(1, 0, 2); bF1 = LDB(1, 0, 3);
    if (nl) STG_B(0, 1, t2);
    BARRIER(); WAITLGKM(); MFMA16(1); BARRIER();
#pragma unroll
    for (int mi = 0; mi < 8; ++mi) aF[mi] = LDA(1, 1, mi);
    bF0 = LDB(1, 1, 0); bF1 = LDB(1, 1, 1);
    if (nl) STG_A(1, 0, t3);
    BARRIER(); WAITLGKM(); MFMA16(0); BARRIER();
    bF0 = LDB(1, 1, 2); bF1 = LDB(1, 1, 3);
    if (nl) STG_B(1, 0, t3);
    BARRIER(); WAITLGKM(); MFMA16(1);
    VMCNT4();
    BARRIER();
  }
#undef STG_A
#undef STG_B
#undef LDA
#undef LDB
#undef MFMA16

  uint16_t* Cb = out0 + (size_t)(n0 >> 11) * 16777216;
  const int r0 = m0 + wm * 128 + (l >> 4) * 4;
  const int c0 = (n0 & 2047) + wn * 64 + fr;
#pragma unroll
  for (int mi = 0; mi < 8; ++mi)
#pragma unroll
    for (int nj = 0; nj < 4; ++nj)
#pragma unroll
      for (int p = 0; p < 4; ++p) {
        const int row = r0 + mi * 16 + p;
        const int col = c0 + nj * 16;
        Cb[(size_t)row * 2048 + col] = f2b(acc[mi][nj][p]);
      }
}

// ---------------------------------------------------------------------------
// Final GEMM, 8-phase port (NEW): C[M,N]fp32 = A @ W^T, BM=256 BN=128 BK=64.
// LDS 96KB: A[2][2][256*32] + B[2][2][128*32]. 8 waves (2x4), wave tile
// 128x32 -> 8mi x 2nj frags. 4 phases per iteration (2 K-tiles), each phase:
//   {8 A-reads + 2 B-reads (one khalf), stage one khalf PAIR (A 2 gloads +
//    B 1 gload), barrier, lgkmcnt(0)+pin, setprio(1), 16 MFMA, setprio(0),
//    vmcnt(6), barrier}.
// Stage->read distance is uniformly 3 phases (ph1 stages s1k1@t1 read ph4;
// ph2: s0k0@t2 read next-ph1; ph3: s0k1@t2 read next-ph2; ph4: s1k0@t3 read
// next-ph3). vmcnt(6) at each phase tail leaves the 2 newest stages (6 loads)
// in flight => the 3-back stage has landed before its reader. Target-dead:
// every staging target was last read exactly 3 phases earlier (>=1 barrier).
// Prologue: s0k0@t0, s0k1@t0, s1k0@t1 (9 gloads), vmcnt(0), barrier.
// Last iteration: ph1 still stages s1k1@t1 (read ph4); ph2/3/4 skip staging;
// tails descend vmcnt(6)->(3)->(0).
// Same swizzle as fused3: ssw valid for A rows w*32+(l>>2) AND B rows
// w*16+(l>>2) ((row>>1)&3 == (l>>3)&3 in both since 16w, 8w are 0 mod 4... 
// 8w mod 4 == 0). k-ascending accumulation -> absmax must stay bit-exact.
// ---------------------------------------------------------------------------
__global__ __launch_bounds__(512) void gemm_fin(const uint16_t* __restrict__ A,
                                                const uint16_t* __restrict__ W,
                                                float* __restrict__ C,
                                                int Nd, int K) {
  __shared__ uint16_t Al[2][2][8192];   // [slot][khalf][256*32]
  __shared__ uint16_t Bl[2][2][4096];   // [slot][khalf][128*32]
  const int tid = threadIdx.x;
  const int l = tid & 63, w = tid >> 6;
  const int wm = w >> 2, wn = w & 3;
  const int m0 = blockIdx.x * 256, n0 = blockIdx.y * 128;
  const int fr = l & 15;
  const int pu = (((l >> 4) ^ ((fr >> 1) & 3)) * 8);
  const int ssw = ((l & 3) ^ ((l >> 3) & 3)) * 8;
  const uint16_t* aS = A + (size_t)(m0 + w * 32 + (l >> 2)) * K + ssw;
  const uint16_t* wS = W + (size_t)(n0 + w * 16 + (l >> 2)) * K + ssw;

  f32x4 acc[8][2];
#pragma unroll
  for (int mi = 0; mi < 8; ++mi)
#pragma unroll
    for (int nj = 0; nj < 2; ++nj) {
      f32x4 z = {0.f, 0.f, 0.f, 0.f};
      acc[mi][nj] = z;
    }

#define FSTG(S, KH, KT) do {                                                 \
    const uint16_t* _pa = aS + (size_t)(KT) * 64 + (KH) * 32;                \
    gload16(_pa,                  &Al[S][KH][(w * 32) * 32]);                \
    gload16(_pa + (size_t)16 * K, &Al[S][KH][(w * 32 + 16) * 32]);           \
    const uint16_t* _pb = wS + (size_t)(KT) * 64 + (KH) * 32;                \
    gload16(_pb,                  &Bl[S][KH][(w * 16) * 32]);                \
  } while (0)
#define FLDA(S, KH, MI) (*(const s16x8*)&Al[S][KH][(wm * 128 + (MI) * 16 + fr) * 32 + pu])
#define FLDB(S, KH, NJ) (*(const s16x8*)&Bl[S][KH][(wn * 32 + (NJ) * 16 + fr) * 32 + pu])
#define FPHASE(RS, RKH) do {                                                 \
    _Pragma("unroll")                                                        \
    for (int mi = 0; mi < 8; ++mi) aF[mi] = FLDA(RS, RKH, mi);               \
    bF0 = FLDB(RS, RKH, 0); bF1 = FLDB(RS, RKH, 1);                          \
  } while (0)
#define FMFMA() do {                                                         \
    __builtin_amdgcn_s_setprio(1);                                           \
    _Pragma("unroll")                                                        \
    for (int mi = 0; mi < 8; ++mi)                                           \
      acc[mi][0] = __builtin_amdgcn_mfma_f32_16x16x32_bf16(                  \
          aF[mi], bF0, acc[mi][0], 0, 0, 0);                                 \
    _Pragma("unroll")                                                        \
    for (int mi = 0; mi < 8; ++mi)                                           \
      acc[mi][1] = __builtin_amdgcn_mfma_f32_16x16x32_bf16(                  \
          aF[mi], bF1, acc[mi][1], 0, 0, 0);                                 \
    __builtin_amdgcn_s_setprio(0);                                           \
  } while (0)

  // prologue: t0 both halves + t1 kh0 (9 gloads), drain, publish
  FSTG(0, 0, 0); FSTG(0, 1, 0); FSTG(1, 0, 1);
  VMCNT0();
  BARRIER();

  const int NI = K / 128;
  s16x8 aF[8], bF0, bF1;

  for (int i = 0; i < NI; ++i) {
    const bool nl = (i < NI - 1);
    const size_t t1 = 2 * i + 1, t2 = 2 * i + 2, t3 = 2 * i + 3;
    // ph1: read s0k0; stage s1k1@t1 (read at ph4 this iter)
    FPHASE(0, 0);
    FSTG(1, 1, t1);
    BARRIER(); WAITLGKM(); FMFMA();
    VMCNT6();
    BARRIER();
    // ph2: read s0k1; stage s0k0@t2 (read next ph1)
    FPHASE(0, 1);
    if (nl) FSTG(0, 0, t2);
    BARRIER(); WAITLGKM(); FMFMA();
    if (nl) VMCNT6(); else VMCNT3();
    BARRIER();
    // ph3: read s1k0; stage s0k1@t2 (read next ph2)
    FPHASE(1, 0);
    if (nl) FSTG(0, 1, t2);
    BARRIER(); WAITLGKM(); FMFMA();
    if (nl) VMCNT6(); else VMCNT0();
    BARRIER();
    // ph4: read s1k1; stage s1k0@t3 (read next ph3)
    FPHASE(1, 1);
    if (nl) FSTG(1, 0, t3);
    BARRIER(); WAITLGKM(); FMFMA();
    if (nl) VMCNT6();
    BARRIER();
  }
#undef FSTG
#undef FLDA
#undef FLDB
#undef FPHASE
#undef FMFMA

  const int r0 = m0 + wm * 128 + (l >> 4) * 4;
  const int c0 = n0 + wn * 32 + fr;
#pragma unroll
  for (int mi = 0; mi < 8; ++mi)
#pragma unroll
    for (int nj = 0; nj < 2; ++nj)
#pragma unroll
      for (int p = 0; p < 4; ++p)
        C[(size_t)(r0 + mi * 16 + p) * Nd + c0 + nj * 16] = acc[mi][nj][p];
}

// ---------------------------------------------------------------------------
// RoPE on fused bf16 qk rows (stride QKS) in place; q scaled by 1/16.
// ---------------------------------------------------------------------------
__global__ void rope_kernel(uint16_t* __restrict__ qk) {
  const int idx = blockIdx.x * 256 + threadIdx.x;   // < B*N*H*128
  const int i = idx & 127;
  const int h = (idx >> 7) & 3;
  const int n = (idx >> 9) & (Nn - 1);
  const int b = idx >> 21;
  const size_t base = ((size_t)(b * Nn + n)) * QKS + h * DK;
  const float invf = (float)exp((double)i * -0.071955784156063938);  // 1e4^(-i/128)
  const float theta = (float)n * invf;
  float sn, cs;
  sincosf(theta, &sn, &cs);
  float x1 = b2f(qk[base + i]), x2 = b2f(qk[base + 128 + i]);
  qk[base + i]       = f2b((x1 * cs - x2 * sn) * 0.0625f);
  qk[base + 128 + i] = f2b((x2 * cs + x1 * sn) * 0.0625f);
  x1 = b2f(qk[base + 1024 + i]); x2 = b2f(qk[base + 1024 + 128 + i]);
  qk[base + 1024 + i]       = f2b(x1 * cs - x2 * sn);
  qk[base + 1024 + 128 + i] = f2b(x2 * cs + x1 * sn);
}

// ---------------------------------------------------------------------------
// v transpose: vt[bh][w][n] = v[b][n][h*DV + w].  64x64 LDS tiles.
// ---------------------------------------------------------------------------
__global__ __launch_bounds__(256) void transpose_v(const uint16_t* __restrict__ v,
                                                   uint16_t* __restrict__ vt) {
  const int nt = blockIdx.x & 63;
  const int wt = (blockIdx.x >> 6) & 7;
  const int bh = blockIdx.x >> 9;
  const int b = bh >> 2, h = bh & 3;
  __shared__ uint16_t t[64][72];
  const int lr = threadIdx.x >> 2, lc = (threadIdx.x & 3) * 16;
  const uint16_t* src = v + ((size_t)(b * Nn + nt * 64 + lr)) * DM + h * DV + wt * 64 + lc;
  *(uint4*)&t[lr][lc]     = *(const uint4*)src;
  *(uint4*)&t[lr][lc + 8] = *(const uint4*)(src + 8);
  __syncthreads();
  uint16_t out[16];
#pragma unroll
  for (int e = 0; e < 16; ++e) out[e] = t[lc + e][lr];
  uint16_t* dst = vt + ((size_t)bh * 512 + wt * 64 + lr) * 4096 + nt * 64 + lc;
  *(uint4*)dst       = *(uint4*)&out[0];
  *(uint4*)(dst + 8) = *(uint4*)&out[8];
}

// ---------------------------------------------------------------------------
// k transpose + gamma-scale: kt[bh][d][n] = gamma_h^(63-(n&63)) * k[b][n][d]
// ---------------------------------------------------------------------------
__global__ __launch_bounds__(256) void transpose_k(const uint16_t* __restrict__ qk,
                                                   uint16_t* __restrict__ kt) {
  const int nt = blockIdx.x & 63;
  const int dt = (blockIdx.x >> 6) & 3;
  const int bh = blockIdx.x >> 8;
  const int b = bh >> 2, h = bh & 3;
  __shared__ uint16_t t[64][72];
  const int lr = threadIdx.x >> 2, lc = (threadIdx.x & 3) * 16;
  const uint16_t* src = qk + ((size_t)(b * Nn + nt * 64 + lr)) * QKS + 1024 + h * DK + dt * 64 + lc;
  *(uint4*)&t[lr][lc]     = *(const uint4*)src;
  *(uint4*)&t[lr][lc + 8] = *(const uint4*)(src + 8);
  __syncthreads();
  const float l2g = log2f(1.f - exp2f(-5.f - (float)h));
  uint16_t out[16];
#pragma unroll
  for (int e = 0; e < 16; ++e)
    out[e] = f2b(b2f(t[lc + e][lr]) * exp2f((float)(63 - (lc + e)) * l2g));
  uint16_t* dst = kt + ((size_t)bh * 256 + dt * 64 + lr) * 4096 + nt * 64 + lc;
  *(uint4*)dst       = *(uint4*)&out[0];
  *(uint4*)(dst + 8) = *(uint4*)&out[8];
}

// ---------------------------------------------------------------------------
// Intra-chunk attention via MFMA: attn[bh][c][i][j] (bf16).
// ---------------------------------------------------------------------------
__global__ __launch_bounds__(256) void attn_mfma(const uint16_t* __restrict__ qk,
                                                 uint16_t* __restrict__ attn) {
  const int c  = blockIdx.x & 63;
  const int bh = blockIdx.x >> 6;
  const int b = bh >> 2, h = bh & 3;
  const int tid = threadIdx.x;
  const int l = tid & 63, w = tid >> 6;
  const int fr = l & 15, fk = (l >> 4) * 8;
  const int n0 = c * CH;
  const uint16_t* qbase = qk + ((size_t)(b * Nn + n0)) * QKS + h * DK;
  const uint16_t* kbase = qbase + 1024;
  f32x4 acc[4];
#pragma unroll
  for (int nj = 0; nj < 4; ++nj) {
    f32x4 z = {0.f, 0.f, 0.f, 0.f};
    acc[nj] = z;
  }
#pragma unroll
  for (int ks = 0; ks < 8; ++ks) {
    s16x8 qf = *(const s16x8*)(qbase + (size_t)(w * 16 + fr) * QKS + ks * 32 + fk);
    s16x8 kf[4];
#pragma unroll
    for (int nj = 0; nj < 4; ++nj)
      kf[nj] = *(const s16x8*)(kbase + (size_t)(nj * 16 + fr) * QKS + ks * 32 + fk);
#pragma unroll
    for (int nj = 0; nj < 4; ++nj)
      acc[nj] = __builtin_amdgcn_mfma_f32_16x16x32_bf16(qf, kf[nj], acc[nj], 0, 0, 0);
  }
  const float l2g = log2f(1.f - exp2f(-5.f - (float)h));
  uint16_t* ab = attn + ((size_t)bh * 64 + c) * 4096;
  const int rbase = (l >> 4) * 4;
#pragma unroll
  for (int pp = 0; pp < 4; ++pp) {
    const int i = w * 16 + rbase + pp;
#pragma unroll
    for (int nj = 0; nj < 4; ++nj) {
      const int j = nj * 16 + fr;
      const float val = (i >= j) ? acc[nj][pp] * exp2f((float)(i - j) * l2g) : 0.f;
      ab[(size_t)i * 64 + j] = f2b(val);
    }
  }
}

// ---------------------------------------------------------------------------
// Kernel A: U_c^T[w,d] = sum_j vt[w,j] * kt[d,j]  (direct-global fragments)
// ---------------------------------------------------------------------------
__global__ __launch_bounds__(256) void chunk_outer(const uint16_t* __restrict__ kt,
                                                   const uint16_t* __restrict__ vt,
                                                   uint16_t* __restrict__ U, int p) {
  const int c  = blockIdx.x & 63;
  const int bh = blockIdx.x >> 6;
  const int tid = threadIdx.x;
  const int l = tid & 63, w = tid >> 6;
  const int wrow = (w >> 1) * 64;     // w' base (M)
  const int wcol = (w & 1) * 128;     // d  base (N)
  const int fr = l & 15, fk = (l >> 4) * 8;
  const int n0 = c * CH;
  const uint16_t* vtb = vt + ((size_t)bh * 512 + p * 128) * 4096 + n0;
  const uint16_t* ktb = kt + ((size_t)bh * 256) * 4096 + n0;
  f32x4 acc[4][8];
#pragma unroll
  for (int mi = 0; mi < 4; ++mi)
#pragma unroll
    for (int nj = 0; nj < 8; ++nj) {
      f32x4 z = {0.f, 0.f, 0.f, 0.f};
      acc[mi][nj] = z;
    }
#pragma unroll
  for (int ks = 0; ks < 2; ++ks) {
    s16x8 af[4], bf8[8];
#pragma unroll
    for (int mi = 0; mi < 4; ++mi)
      af[mi] = *(const s16x8*)(vtb + (size_t)(wrow + mi * 16 + fr) * 4096 + ks * 32 + fk);
#pragma unroll
    for (int nj = 0; nj < 8; ++nj)
      bf8[nj] = *(const s16x8*)(ktb + (size_t)(wcol + nj * 16 + fr) * 4096 + ks * 32 + fk);
#pragma unroll
    for (int mi = 0; mi < 4; ++mi)
#pragma unroll
      for (int nj = 0; nj < 8; ++nj)
        acc[mi][nj] = __builtin_amdgcn_mfma_f32_16x16x32_bf16(af[mi], bf8[nj],
                                                              acc[mi][nj], 0, 0, 0);
  }
  uint16_t* Ub = U + (size_t)bh * 2097152 + (size_t)c * 32768;
  const int rbase = (l >> 4) * 4;
#pragma unroll
  for (int mi = 0; mi < 4; ++mi)
#pragma unroll
    for (int nj = 0; nj < 8; ++nj)
#pragma unroll
      for (int pp = 0; pp < 4; ++pp) {
        const int wq = wrow + mi * 16 + rbase + pp;
        const int d  = wcol + nj * 16 + fr;
        Ub[(size_t)wq * 256 + d] = f2b(acc[mi][nj][pp]);
      }
}

// ---------------------------------------------------------------------------
// Kernel B: in-place state scan (slot c -> S_c), 8-batch load prefetch.
// ---------------------------------------------------------------------------
__global__ __launch_bounds__(256) void state_scan(uint16_t* __restrict__ U) {
  const int gid = blockIdx.x * 256 + threadIdx.x;   // < 8*32768 = 262144
  const int bh = gid >> 15;
  const int e  = gid & 32767;
  const int h  = bh & 3;
  const float l2g = log2f(1.f - exp2f(-5.f - (float)h));
  const float gC = exp2f(64.f * l2g);
  uint16_t* p = U + (size_t)bh * 2097152 + e;
  float S = 0.f;
  for (int cb = 0; cb < 8; ++cb) {
    uint16_t* base = p + (size_t)cb * 8 * 32768;
    float u[8];
#pragma unroll
    for (int ee = 0; ee < 8; ++ee) u[ee] = b2f(base[(size_t)ee * 32768]);
#pragma unroll
    for (int ee = 0; ee < 8; ++ee) {
      base[(size_t)ee * 32768] = f2b(S);
      S = gC * S + u[ee];
    }
  }
}

// ---------------------------------------------------------------------------
// Kernel C: o[i,w] = (attn_c @ v_c)[i,w] + gamma^(i+1)*(q_c @ S_c)[i,w]
// ---------------------------------------------------------------------------
__global__ __launch_bounds__(256) void scan_out(const uint16_t* __restrict__ qk,
                                                const uint16_t* __restrict__ vt,
                                                const uint16_t* __restrict__ attn,
                                                const uint16_t* __restrict__ U,
                                                uint16_t* __restrict__ o, int p) {
  const int c  = blockIdx.x & 63;
  const int bh = blockIdx.x >> 6;
  const int b = bh >> 2, h = bh & 3;
  const int tid = threadIdx.x;
  const int l = tid & 63, wv = tid >> 6;
  const int wcol = wv * 32;                 // output col base (within pass 128)
  const int fr = l & 15, fk = (l >> 4) * 8;
  const int n0 = c * CH;
  f32x4 aQS[4][2], aPV[4][2];
#pragma unroll
  for (int mi = 0; mi < 4; ++mi)
#pragma unroll
    for (int nj = 0; nj < 2; ++nj) {
      f32x4 z = {0.f, 0.f, 0.f, 0.f};
      aQS[mi][nj] = z; aPV[mi][nj] = z;
    }
  const uint16_t* qbase = qk + ((size_t)(b * Nn + n0)) * QKS + h * DK;
  const uint16_t* Ub = U + (size_t)bh * 2097152 + (size_t)c * 32768;
  // q @ S  (K = 256)
#pragma unroll
  for (int ks = 0; ks < 8; ++ks) {
    s16x8 qf[4], sf[2];
#pragma unroll
    for (int mi = 0; mi < 4; ++mi)
      qf[mi] = *(const s16x8*)(qbase + (size_t)(mi * 16 + fr) * QKS + ks * 32 + fk);
#pragma unroll
    for (int nj = 0; nj < 2; ++nj)
      sf[nj] = *(const s16x8*)(Ub + (size_t)(wcol + nj * 16 + fr) * 256 + ks * 32 + fk);
#pragma unroll
    for (int mi = 0; mi < 4; ++mi)
#pragma unroll
      for (int nj = 0; nj < 2; ++nj)
        aQS[mi][nj] = __builtin_amdgcn_mfma_f32_16x16x32_bf16(qf[mi], sf[nj],
                                                              aQS[mi][nj], 0, 0, 0);
  }
  // attn @ v  (K = 64)
  const uint16_t* ab = attn + ((size_t)bh * 64 + c) * 4096;
  const uint16_t* vtb = vt + ((size_t)bh * 512 + p * 128) * 4096 + n0;
#pragma unroll
  for (int ks = 0; ks < 2; ++ks) {
    s16x8 af[4], vf[2];
#pragma unroll
    for (int mi = 0; mi < 4; ++mi)
      af[mi] = *(const s16x8*)(ab + (size_t)(mi * 16 + fr) * 64 + ks * 32 + fk);
#pragma unroll
    for (int nj = 0; nj < 2; ++nj)
      vf[nj] = *(const s16x8*)(vtb + (size_t)(wcol + nj * 16 + fr) * 4096 + ks * 32 + fk);
#pragma unroll
    for (int mi = 0; mi < 4; ++mi)
#pragma unroll
      for (int nj = 0; nj < 2; ++nj)
        aPV[mi][nj] = __builtin_amdgcn_mfma_f32_16x16x32_bf16(af[mi], vf[nj],
                                                              aPV[mi][nj], 0, 0, 0);
  }
  const float l2g = log2f(1.f - exp2f(-5.f - (float)h));
  const int rbase = (l >> 4) * 4;
#pragma unroll
  for (int mi = 0; mi < 4; ++mi)
#pragma unroll
    for (int pp = 0; pp < 4; ++pp) {
      const int i = mi * 16 + rbase + pp;
      const float gi = exp2f((float)(i + 1) * l2g);
#pragma unroll
      for (int nj = 0; nj < 2; ++nj) {
        const int wc_ = wcol + nj * 16 + fr;
        const float val = aPV[mi][nj][pp] + gi * aQS[mi][nj][pp];
        o[((size_t)(b * Nn + n0 + i)) * DM + h * DV + p * 128 + wc_] = f2b(val);
      }
    }
}

// ---------------------------------------------------------------------------
// GroupNorm over DV per (b,n,h) + SiLU gate (o bf16), in place into g.
// ---------------------------------------------------------------------------
__global__ __launch_bounds__(256) void gn_gate(const uint16_t* __restrict__ o,
                                               uint16_t* __restrict__ g,
                                               const float* __restrict__ gw) {
  const int bn = blockIdx.x;
  const int tid = threadIdx.x;
  const int h = tid >> 6;
  const int lane = tid & 63;
  const size_t base = (size_t)bn * DM + h * DV + lane * 8;
  uint4 ov4 = *(const uint4*)&o[base];
  float ov[8] = { b2f((uint16_t)ov4.x), b2f((uint16_t)(ov4.x >> 16)),
                  b2f((uint16_t)ov4.y), b2f((uint16_t)(ov4.y >> 16)),
                  b2f((uint16_t)ov4.z), b2f((uint16_t)(ov4.z >> 16)),
                  b2f((uint16_t)ov4.w), b2f((uint16_t)(ov4.w >> 16)) };
  float ss = 0.f;
#pragma unroll
  for (int e = 0; e < 8; ++e) ss += ov[e] * ov[e];
#pragma unroll
  for (int m = 1; m < 64; m <<= 1) ss += __shfl_xor(ss, m, 64);
  const float r = rsqrtf(ss * (1.f / 512.f) + 1e-5f);
  uint4 gv = *(const uint4*)&g[base];
  float gf[8] = { b2f((uint16_t)gv.x), b2f((uint16_t)(gv.x >> 16)),
                  b2f((uint16_t)gv.y), b2f((uint16_t)(gv.y >> 16)),
                  b2f((uint16_t)gv.z), b2f((uint16_t)(gv.z >> 16)),
                  b2f((uint16_t)gv.w), b2f((uint16_t)(gv.w >> 16)) };
  const float* gwp = gw + lane * 8;
  uint16_t res[8];
#pragma unroll
  for (int e = 0; e < 8; ++e) {
    float sil = gf[e] / (1.f + expf(-gf[e]));
    res[e] = f2b(ov[e] * r * gwp[e] * sil);
  }
  uint4 outv;
  outv.x = (uint32_t)res[0] | ((uint32_t)res[1] << 16);
  outv.y = (uint32_t)res[2] | ((uint32_t)res[3] << 16);
  outv.z = (uint32_t)res[4] | ((uint32_t)res[5] << 16);
  outv.w = (uint32_t)res[6] | ((uint32_t)res[7] << 16);
  *(uint4*)&g[base] = outv;
}

// ---------------------------------------------------------------------------
// ws layout (MB), peak 160 (proven size). Overlays, write-before-read ordered:
//   [  0, 32)  xb (dead after fused GEMM)            -> U (scan)
//   [ 32, 64)  qkb   [ 64, 96) vb -> kt[64,80) attn[80,84) wob[84,92)
//   [ 96,128)  gb
//   [128,152)  wall (stacked Wq;Wk;Wv;Wg, dead after fused GEMM)
//                                                    -> vt[128,160)
// o16 (bf16) lives in d_out's first 32MB until gn_gate; final GEMM overwrites
// d_out fp32. Every region fully written before read -> graph-replay safe.
// ---------------------------------------------------------------------------
extern "C" void kernel_launch(void* const* d_in, const int* in_sizes, int n_in,
                              void* d_out, int out_size, void* d_ws, size_t ws_size,
                              hipStream_t stream) {
  const float* x  = (const float*)d_in[0];
  const float* Wq = (const float*)d_in[1];
  const float* Wk = (const float*)d_in[2];
  const float* Wv = (const float*)d_in[3];
  const float* Wg = (const float*)d_in[4];
  const float* Wo = (const float*)d_in[5];
  const float* gw = (const float*)d_in[6];

  char* base = (char*)d_ws;
  uint16_t* xb   = (uint16_t*)(base);                       // [0,32)
  uint16_t* U    = (uint16_t*)(base);                       // overlays xb (scan)
  uint16_t* qkb  = (uint16_t*)(base + ((size_t)32 << 20));  // [32,64)
  uint16_t* vb   = (uint16_t*)(base + ((size_t)64 << 20));  // [64,96)
  uint16_t* kt   = (uint16_t*)(base + ((size_t)64 << 20));  // overlays vb
  uint16_t* attn = (uint16_t*)(base + ((size_t)80 << 20));  // overlays vb
  uint16_t* wob  = (uint16_t*)(base + ((size_t)84 << 20));  // overlays vb
  uint16_t* gb   = (uint16_t*)(base + ((size_t)96 << 20));  // [96,128)
  uint16_t* wall = (uint16_t*)(base + ((size_t)128 << 20)); // [128,152)
  uint16_t* vt   = (uint16_t*)(base + ((size_t)128 << 20)); // overlays wall
  uint16_t* qb   = qkb;                    // q = cols 0-1023
  uint16_t* o16  = (uint16_t*)d_out;       // bf16 o scratch (first 32MB)

  dim3 blk(256), blkG(512);
  // phase 1: conversions + ONE fused GEMM (qk|v|g), 768 blocks
  conv_f2b<<<dim3(8192), blk, 0, stream>>>(x, xb, M * DM / 8);
  conv_w4<<<dim3(6144), blk, 0, stream>>>(Wq, Wk, Wv, Wg, wall);
  gemm_fused3<<<dim3(M/256, 6144/256), blkG, 0, stream>>>(xb, wall, qkb, DM);
  // phase 2: rope; transposes (vb, wall die); attn
  rope_kernel<<<dim3((Bb*Nn*Hh*128)/256), blk, 0, stream>>>(qkb);
  transpose_v<<<dim3(8*8*64), blk, 0, stream>>>(vb, vt);     // vb -> dead
  conv_f2b<<<dim3(2048), blk, 0, stream>>>(Wo, wob, DM * DM / 8);
  transpose_k<<<dim3(8*4*64), blk, 0, stream>>>(qkb, kt);
  attn_mfma<<<dim3(Bb*Hh*NC), blk, 0, stream>>>(qkb, attn);
  // scan: 4 passes of 128 dv cols; U overlays dead xb
  for (int p = 0; p < 4; ++p) {
    chunk_outer<<<dim3(Bb*Hh*NC),  blk, 0, stream>>>(kt, vt, U, p);
    state_scan<<<dim3(1024),       blk, 0, stream>>>(U);
    scan_out<<<dim3(Bb*Hh*NC),     blk, 0, stream>>>(qb, vt, attn, U, o16, p);
  }
  // epilogue
  gn_gate<<<dim3(M), blk, 0, stream>>>(o16, gb, gw);
  gemm_fin<<<dim3(M/256, DM/128), blkG, 0, stream>>>(gb, wob, (float*)d_out, DM, DM);
}

// Round 14
// 545.050 us; speedup vs baseline: 1.0269x; 1.0269x over previous
//
#include <hip/hip_runtime.h>
#include <hip/hip_bf16.h>
#include <stdint.h>

// Problem constants (MultiScaleRetention: B=2, N=4096, D_MODEL=2048, H=4)
constexpr int Bb   = 2;
constexpr int Nn   = 4096;
constexpr int DM   = 2048;
constexpr int Hh   = 4;
constexpr int DK   = 256;    // KEY_DIM / H
constexpr int DV   = 512;    // D_MODEL / H
constexpr int QKS  = 2048;   // fused q|k row stride (q cols 0-1023, k cols 1024-2047)
constexpr int CH   = 64;     // chunk
constexpr int NC   = Nn / CH;   // 64 chunks
constexpr int M    = Bb * Nn;   // 8192 rows

typedef __attribute__((ext_vector_type(8))) short s16x8;   // 8 bf16 (4 VGPRs)
typedef __attribute__((ext_vector_type(4))) float f32x4;

__device__ __forceinline__ float b2f(uint16_t h) {
  return __uint_as_float(((uint32_t)h) << 16);
}
__device__ __forceinline__ uint16_t f2b(float f) {   // RNE, finite inputs
  uint32_t u = __float_as_uint(f);
  return (uint16_t)((u + 0x7fffu + ((u >> 16) & 1u)) >> 16);
}

// async global->LDS, 16B per lane; LDS dest = wave-uniform base + lane*16
__device__ __forceinline__ void gload16(const void* g, void* l) {
  __builtin_amdgcn_global_load_lds(
      (const __attribute__((address_space(1))) void*)g,
      (__attribute__((address_space(3))) void*)l, 16, 0, 0);
}

#define BARRIER()  asm volatile("s_barrier" ::: "memory")
#define WAITLGKM() do { asm volatile("s_waitcnt lgkmcnt(0)" ::: "memory"); \
                        __builtin_amdgcn_sched_barrier(0); } while (0)
#define VMCNT4()   asm volatile("s_waitcnt vmcnt(4)" ::: "memory")
#define VMCNT0()   asm volatile("s_waitcnt vmcnt(0)" ::: "memory")

// ---------------------------------------------------------------------------
// fp32 -> bf16 bulk convert, 8 elems/thread
// ---------------------------------------------------------------------------
__global__ __launch_bounds__(256) void conv_f2b(const float* __restrict__ s,
                                                uint16_t* __restrict__ d, int n8) {
  int i = blockIdx.x * 256 + threadIdx.x;
  if (i >= n8) return;
  const float4* sp = (const float4*)s;
  float4 a = sp[2 * i], b = sp[2 * i + 1];
  uint4 o;
  o.x = (uint32_t)f2b(a.x) | ((uint32_t)f2b(a.y) << 16);
  o.y = (uint32_t)f2b(a.z) | ((uint32_t)f2b(a.w) << 16);
  o.z = (uint32_t)f2b(b.x) | ((uint32_t)f2b(b.y) << 16);
  o.w = (uint32_t)f2b(b.z) | ((uint32_t)f2b(b.w) << 16);
  ((uint4*)d)[i] = o;
}

// ---------------------------------------------------------------------------
// fused Wq/Wk/Wv/Wg fp32->bf16 into stacked [6144][2048] bf16. 8 elems/thread.
// ---------------------------------------------------------------------------
__global__ __launch_bounds__(256) void conv_w4(const float* __restrict__ Wq,
                                               const float* __restrict__ Wk,
                                               const float* __restrict__ Wv,
                                               const float* __restrict__ Wg,
                                               uint16_t* __restrict__ dst) {
  const int i = blockIdx.x * 256 + threadIdx.x;   // < 1572864
  const float* s; int off;
  if (i < 262144)       { s = Wq; off = i; }
  else if (i < 524288)  { s = Wk; off = i - 262144; }
  else if (i < 1048576) { s = Wv; off = i - 524288; }
  else                  { s = Wg; off = i - 1048576; }
  const float4* sp = (const float4*)s;
  float4 a = sp[2 * off], b = sp[2 * off + 1];
  uint4 o;
  o.x = (uint32_t)f2b(a.x) | ((uint32_t)f2b(a.y) << 16);
  o.y = (uint32_t)f2b(a.z) | ((uint32_t)f2b(a.w) << 16);
  o.z = (uint32_t)f2b(b.x) | ((uint32_t)f2b(b.y) << 16);
  o.w = (uint32_t)f2b(b.z) | ((uint32_t)f2b(b.w) << 16);
  ((uint4*)dst)[i] = o;
}

// ---------------------------------------------------------------------------
// 256x256 8-PHASE GEMM template (round-12 proven schedule: MfmaUtil 42%,
// bank conflicts 0, absmax bit-exact). Templated ONLY on the epilogue:
//   OBF=true : bf16 out, 3-region select by n0>>11 (fused qk|v|g, 32MB apart)
//   OBF=false: fp32 out, single region stride 2048 (final GEMM)
// Round-13 lesson: the 4-phase BN=128 port regressed (wrong phase geometry:
// 3 gloads/10 ds_reads per phase vs 8 barriers/2 tiles). Reuse THIS geometry.
// ---------------------------------------------------------------------------
template<bool OBF>
__global__ __launch_bounds__(512) void gemm8p(const uint16_t* __restrict__ A,
                                              const uint16_t* __restrict__ W,
                                              void* __restrict__ Cout,
                                              int K) {
  __shared__ uint16_t Al[2][2][8192];   // [slot][khalf][256*32]
  __shared__ uint16_t Bl[2][2][8192];
  const int tid = threadIdx.x;
  const int l = tid & 63, w = tid >> 6;
  const int wm = w >> 2, wn = w & 3;
  const int m0 = blockIdx.x * 256, n0 = blockIdx.y * 256;
  const int fr = l & 15;
  const int pu = (((l >> 4) ^ ((fr >> 1) & 3)) * 8);
  const int ssw = ((l & 3) ^ ((l >> 3) & 3)) * 8;
  const uint16_t* aS = A + (size_t)(m0 + w * 32 + (l >> 2)) * K + ssw;
  const uint16_t* wS = W + (size_t)(n0 + w * 32 + (l >> 2)) * K + ssw;

  f32x4 acc[8][4];
#pragma unroll
  for (int mi = 0; mi < 8; ++mi)
#pragma unroll
    for (int nj = 0; nj < 4; ++nj) {
      f32x4 z = {0.f, 0.f, 0.f, 0.f};
      acc[mi][nj] = z;
    }

#define STG_A(S, KH, KT) do {                                                \
    const uint16_t* _p = aS + (size_t)(KT) * 64 + (KH) * 32;                 \
    gload16(_p,                   &Al[S][KH][(w * 32) * 32]);                \
    gload16(_p + (size_t)16 * K,  &Al[S][KH][(w * 32 + 16) * 32]);           \
  } while (0)
#define STG_B(S, KH, KT) do {                                                \
    const uint16_t* _p = wS + (size_t)(KT) * 64 + (KH) * 32;                 \
    gload16(_p,                   &Bl[S][KH][(w * 32) * 32]);                \
    gload16(_p + (size_t)16 * K,  &Bl[S][KH][(w * 32 + 16) * 32]);           \
  } while (0)
#define LDA(S, KH, MI) (*(const s16x8*)&Al[S][KH][(wm * 128 + (MI) * 16 + fr) * 32 + pu])
#define LDB(S, KH, NJ) (*(const s16x8*)&Bl[S][KH][(wn * 64 + (NJ) * 16 + fr) * 32 + pu])
#define MFMA16(Q) do {                                                       \
    __builtin_amdgcn_s_setprio(1);                                           \
    _Pragma("unroll")                                                        \
    for (int mi = 0; mi < 8; ++mi)                                           \
      acc[mi][2*(Q)] = __builtin_amdgcn_mfma_f32_16x16x32_bf16(              \
          aF[mi], bF0, acc[mi][2*(Q)], 0, 0, 0);                             \
    _Pragma("unroll")                                                        \
    for (int mi = 0; mi < 8; ++mi)                                           \
      acc[mi][2*(Q)+1] = __builtin_amdgcn_mfma_f32_16x16x32_bf16(            \
          aF[mi], bF1, acc[mi][2*(Q)+1], 0, 0, 0);                           \
    __builtin_amdgcn_s_setprio(0);                                           \
  } while (0)

  STG_A(0, 0, 0); STG_B(0, 0, 0); STG_A(0, 1, 0); STG_B(0, 1, 0);
  STG_A(1, 0, 1); STG_B(1, 0, 1);
  VMCNT0();
  BARRIER();

  const int NI = K / 128;
  s16x8 aF[8], bF0, bF1;

  for (int i = 0; i < NI; ++i) {
    const bool nl = (i < NI - 1);
    const size_t t1 = 2 * i + 1, t2 = 2 * i + 2, t3 = 2 * i + 3;
#pragma unroll
    for (int mi = 0; mi < 8; ++mi) aF[mi] = LDA(0, 0, mi);
    bF0 = LDB(0, 0, 0); bF1 = LDB(0, 0, 1);
    STG_A(1, 1, t1);
    BARRIER(); WAITLGKM(); MFMA16(0); BARRIER();
    bF0 = LDB(0, 0, 2); bF1 = LDB(0, 0, 3);
    STG_B(1, 1, t1);
    BARRIER(); WAITLGKM(); MFMA16(1); BARRIER();
#pragma unroll
    for (int mi = 0; mi < 8; ++mi) aF[mi] = LDA(0, 1, mi);
    bF0 = LDB(0, 1, 0); bF1 = LDB(0, 1, 1);
    if (nl) STG_A(0, 0, t2);
    BARRIER(); WAITLGKM(); MFMA16(0); BARRIER();
    bF0 = LDB(0, 1, 2); bF1 = LDB(0, 1, 3);
    if (nl) STG_B(0, 0, t2);
    BARRIER(); WAITLGKM(); MFMA16(1);
    if (nl) VMCNT4(); else VMCNT0();
    BARRIER();
#pragma unroll
    for (int mi = 0; mi < 8; ++mi) aF[mi] = LDA(1, 0, mi);
    bF0 = LDB(1, 0, 0); bF1 = LDB(1, 0, 1);
    if (nl) STG_A(0, 1, t2);
    BARRIER(); WAITLGKM(); MFMA16(0); BARRIER();
    bF0 = LDB(1, 0, 2); bF1 = LDB(1, 0, 3);
    if (nl) STG_B(0, 1, t2);
    BARRIER(); WAITLGKM(); MFMA16(1); BARRIER();
#pragma unroll
    for (int mi = 0; mi < 8; ++mi) aF[mi] = LDA(1, 1, mi);
    bF0 = LDB(1, 1, 0); bF1 = LDB(1, 1, 1);
    if (nl) STG_A(1, 0, t3);
    BARRIER(); WAITLGKM(); MFMA16(0); BARRIER();
    bF0 = LDB(1, 1, 2); bF1 = LDB(1, 1, 3);
    if (nl) STG_B(1, 0, t3);
    BARRIER(); WAITLGKM(); MFMA16(1);
    VMCNT4();
    BARRIER();
  }
#undef STG_A
#undef STG_B
#undef LDA
#undef LDB
#undef MFMA16

  const int r0 = m0 + wm * 128 + (l >> 4) * 4;
#pragma unroll
  for (int mi = 0; mi < 8; ++mi)
#pragma unroll
    for (int nj = 0; nj < 4; ++nj)
#pragma unroll
      for (int p = 0; p < 4; ++p) {
        const int row = r0 + mi * 16 + p;
        if (OBF) {
          uint16_t* Cb = (uint16_t*)Cout + (size_t)(n0 >> 11) * 16777216;
          const int col = (n0 & 2047) + wn * 64 + fr + nj * 16;
          Cb[(size_t)row * 2048 + col] = f2b(acc[mi][nj][p]);
        } else {
          const int col = n0 + wn * 64 + fr + nj * 16;
          ((float*)Cout)[(size_t)row * 2048 + col] = acc[mi][nj][p];
        }
      }
}

// ---------------------------------------------------------------------------
// RoPE on fused bf16 qk rows (stride QKS) in place; q scaled by 1/16.
// ---------------------------------------------------------------------------
__global__ void rope_kernel(uint16_t* __restrict__ qk) {
  const int idx = blockIdx.x * 256 + threadIdx.x;   // < B*N*H*128
  const int i = idx & 127;
  const int h = (idx >> 7) & 3;
  const int n = (idx >> 9) & (Nn - 1);
  const int b = idx >> 21;
  const size_t base = ((size_t)(b * Nn + n)) * QKS + h * DK;
  const float invf = (float)exp((double)i * -0.071955784156063938);  // 1e4^(-i/128)
  const float theta = (float)n * invf;
  float sn, cs;
  sincosf(theta, &sn, &cs);
  float x1 = b2f(qk[base + i]), x2 = b2f(qk[base + 128 + i]);
  qk[base + i]       = f2b((x1 * cs - x2 * sn) * 0.0625f);
  qk[base + 128 + i] = f2b((x2 * cs + x1 * sn) * 0.0625f);
  x1 = b2f(qk[base + 1024 + i]); x2 = b2f(qk[base + 1024 + 128 + i]);
  qk[base + 1024 + i]       = f2b(x1 * cs - x2 * sn);
  qk[base + 1024 + 128 + i] = f2b(x2 * cs + x1 * sn);
}

// ---------------------------------------------------------------------------
// v transpose: vt[bh][w][n] = v[b][n][h*DV + w].  64x64 LDS tiles.
// ---------------------------------------------------------------------------
__global__ __launch_bounds__(256) void transpose_v(const uint16_t* __restrict__ v,
                                                   uint16_t* __restrict__ vt) {
  const int nt = blockIdx.x & 63;
  const int wt = (blockIdx.x >> 6) & 7;
  const int bh = blockIdx.x >> 9;
  const int b = bh >> 2, h = bh & 3;
  __shared__ uint16_t t[64][72];
  const int lr = threadIdx.x >> 2, lc = (threadIdx.x & 3) * 16;
  const uint16_t* src = v + ((size_t)(b * Nn + nt * 64 + lr)) * DM + h * DV + wt * 64 + lc;
  *(uint4*)&t[lr][lc]     = *(const uint4*)src;
  *(uint4*)&t[lr][lc + 8] = *(const uint4*)(src + 8);
  __syncthreads();
  uint16_t out[16];
#pragma unroll
  for (int e = 0; e < 16; ++e) out[e] = t[lc + e][lr];
  uint16_t* dst = vt + ((size_t)bh * 512 + wt * 64 + lr) * 4096 + nt * 64 + lc;
  *(uint4*)dst       = *(uint4*)&out[0];
  *(uint4*)(dst + 8) = *(uint4*)&out[8];
}

// ---------------------------------------------------------------------------
// k transpose + gamma-scale: kt[bh][d][n] = gamma_h^(63-(n&63)) * k[b][n][d]
// ---------------------------------------------------------------------------
__global__ __launch_bounds__(256) void transpose_k(const uint16_t* __restrict__ qk,
                                                   uint16_t* __restrict__ kt) {
  const int nt = blockIdx.x & 63;
  const int dt = (blockIdx.x >> 6) & 3;
  const int bh = blockIdx.x >> 8;
  const int b = bh >> 2, h = bh & 3;
  __shared__ uint16_t t[64][72];
  const int lr = threadIdx.x >> 2, lc = (threadIdx.x & 3) * 16;
  const uint16_t* src = qk + ((size_t)(b * Nn + nt * 64 + lr)) * QKS + 1024 + h * DK + dt * 64 + lc;
  *(uint4*)&t[lr][lc]     = *(const uint4*)src;
  *(uint4*)&t[lr][lc + 8] = *(const uint4*)(src + 8);
  __syncthreads();
  const float l2g = log2f(1.f - exp2f(-5.f - (float)h));
  uint16_t out[16];
#pragma unroll
  for (int e = 0; e < 16; ++e)
    out[e] = f2b(b2f(t[lc + e][lr]) * exp2f((float)(63 - (lc + e)) * l2g));
  uint16_t* dst = kt + ((size_t)bh * 256 + dt * 64 + lr) * 4096 + nt * 64 + lc;
  *(uint4*)dst       = *(uint4*)&out[0];
  *(uint4*)(dst + 8) = *(uint4*)&out[8];
}

// ---------------------------------------------------------------------------
// Intra-chunk attention via MFMA: attn[bh][c][i][j] (bf16).
// ---------------------------------------------------------------------------
__global__ __launch_bounds__(256) void attn_mfma(const uint16_t* __restrict__ qk,
                                                 uint16_t* __restrict__ attn) {
  const int c  = blockIdx.x & 63;
  const int bh = blockIdx.x >> 6;
  const int b = bh >> 2, h = bh & 3;
  const int tid = threadIdx.x;
  const int l = tid & 63, w = tid >> 6;
  const int fr = l & 15, fk = (l >> 4) * 8;
  const int n0 = c * CH;
  const uint16_t* qbase = qk + ((size_t)(b * Nn + n0)) * QKS + h * DK;
  const uint16_t* kbase = qbase + 1024;
  f32x4 acc[4];
#pragma unroll
  for (int nj = 0; nj < 4; ++nj) {
    f32x4 z = {0.f, 0.f, 0.f, 0.f};
    acc[nj] = z;
  }
#pragma unroll
  for (int ks = 0; ks < 8; ++ks) {
    s16x8 qf = *(const s16x8*)(qbase + (size_t)(w * 16 + fr) * QKS + ks * 32 + fk);
    s16x8 kf[4];
#pragma unroll
    for (int nj = 0; nj < 4; ++nj)
      kf[nj] = *(const s16x8*)(kbase + (size_t)(nj * 16 + fr) * QKS + ks * 32 + fk);
#pragma unroll
    for (int nj = 0; nj < 4; ++nj)
      acc[nj] = __builtin_amdgcn_mfma_f32_16x16x32_bf16(qf, kf[nj], acc[nj], 0, 0, 0);
  }
  const float l2g = log2f(1.f - exp2f(-5.f - (float)h));
  uint16_t* ab = attn + ((size_t)bh * 64 + c) * 4096;
  const int rbase = (l >> 4) * 4;
#pragma unroll
  for (int pp = 0; pp < 4; ++pp) {
    const int i = w * 16 + rbase + pp;
#pragma unroll
    for (int nj = 0; nj < 4; ++nj) {
      const int j = nj * 16 + fr;
      const float val = (i >= j) ? acc[nj][pp] * exp2f((float)(i - j) * l2g) : 0.f;
      ab[(size_t)i * 64 + j] = f2b(val);
    }
  }
}

// ---------------------------------------------------------------------------
// Kernel A: U_c^T[w,d] = sum_j vt[w,j] * kt[d,j]  (direct-global fragments)
// ---------------------------------------------------------------------------
__global__ __launch_bounds__(256) void chunk_outer(const uint16_t* __restrict__ kt,
                                                   const uint16_t* __restrict__ vt,
                                                   uint16_t* __restrict__ U, int p) {
  const int c  = blockIdx.x & 63;
  const int bh = blockIdx.x >> 6;
  const int tid = threadIdx.x;
  const int l = tid & 63, w = tid >> 6;
  const int wrow = (w >> 1) * 64;     // w' base (M)
  const int wcol = (w & 1) * 128;     // d  base (N)
  const int fr = l & 15, fk = (l >> 4) * 8;
  const int n0 = c * CH;
  const uint16_t* vtb = vt + ((size_t)bh * 512 + p * 128) * 4096 + n0;
  const uint16_t* ktb = kt + ((size_t)bh * 256) * 4096 + n0;
  f32x4 acc[4][8];
#pragma unroll
  for (int mi = 0; mi < 4; ++mi)
#pragma unroll
    for (int nj = 0; nj < 8; ++nj) {
      f32x4 z = {0.f, 0.f, 0.f, 0.f};
      acc[mi][nj] = z;
    }
#pragma unroll
  for (int ks = 0; ks < 2; ++ks) {
    s16x8 af[4], bf8[8];
#pragma unroll
    for (int mi = 0; mi < 4; ++mi)
      af[mi] = *(const s16x8*)(vtb + (size_t)(wrow + mi * 16 + fr) * 4096 + ks * 32 + fk);
#pragma unroll
    for (int nj = 0; nj < 8; ++nj)
      bf8[nj] = *(const s16x8*)(ktb + (size_t)(wcol + nj * 16 + fr) * 4096 + ks * 32 + fk);
#pragma unroll
    for (int mi = 0; mi < 4; ++mi)
#pragma unroll
      for (int nj = 0; nj < 8; ++nj)
        acc[mi][nj] = __builtin_amdgcn_mfma_f32_16x16x32_bf16(af[mi], bf8[nj],
                                                              acc[mi][nj], 0, 0, 0);
  }
  uint16_t* Ub = U + (size_t)bh * 2097152 + (size_t)c * 32768;
  const int rbase = (l >> 4) * 4;
#pragma unroll
  for (int mi = 0; mi < 4; ++mi)
#pragma unroll
    for (int nj = 0; nj < 8; ++nj)
#pragma unroll
      for (int pp = 0; pp < 4; ++pp) {
        const int wq = wrow + mi * 16 + rbase + pp;
        const int d  = wcol + nj * 16 + fr;
        Ub[(size_t)wq * 256 + d] = f2b(acc[mi][nj][pp]);
      }
}

// ---------------------------------------------------------------------------
// Kernel B: in-place state scan (slot c -> S_c), 8-batch load prefetch.
// ---------------------------------------------------------------------------
__global__ __launch_bounds__(256) void state_scan(uint16_t* __restrict__ U) {
  const int gid = blockIdx.x * 256 + threadIdx.x;   // < 8*32768 = 262144
  const int bh = gid >> 15;
  const int e  = gid & 32767;
  const int h  = bh & 3;
  const float l2g = log2f(1.f - exp2f(-5.f - (float)h));
  const float gC = exp2f(64.f * l2g);
  uint16_t* p = U + (size_t)bh * 2097152 + e;
  float S = 0.f;
  for (int cb = 0; cb < 8; ++cb) {
    uint16_t* base = p + (size_t)cb * 8 * 32768;
    float u[8];
#pragma unroll
    for (int ee = 0; ee < 8; ++ee) u[ee] = b2f(base[(size_t)ee * 32768]);
#pragma unroll
    for (int ee = 0; ee < 8; ++ee) {
      base[(size_t)ee * 32768] = f2b(S);
      S = gC * S + u[ee];
    }
  }
}

// ---------------------------------------------------------------------------
// Kernel C: o[i,w] = (attn_c @ v_c)[i,w] + gamma^(i+1)*(q_c @ S_c)[i,w]
// ---------------------------------------------------------------------------
__global__ __launch_bounds__(256) void scan_out(const uint16_t* __restrict__ qk,
                                                const uint16_t* __restrict__ vt,
                                                const uint16_t* __restrict__ attn,
                                                const uint16_t* __restrict__ U,
                                                uint16_t* __restrict__ o, int p) {
  const int c  = blockIdx.x & 63;
  const int bh = blockIdx.x >> 6;
  const int b = bh >> 2, h = bh & 3;
  const int tid = threadIdx.x;
  const int l = tid & 63, wv = tid >> 6;
  const int wcol = wv * 32;                 // output col base (within pass 128)
  const int fr = l & 15, fk = (l >> 4) * 8;
  const int n0 = c * CH;
  f32x4 aQS[4][2], aPV[4][2];
#pragma unroll
  for (int mi = 0; mi < 4; ++mi)
#pragma unroll
    for (int nj = 0; nj < 2; ++nj) {
      f32x4 z = {0.f, 0.f, 0.f, 0.f};
      aQS[mi][nj] = z; aPV[mi][nj] = z;
    }
  const uint16_t* qbase = qk + ((size_t)(b * Nn + n0)) * QKS + h * DK;
  const uint16_t* Ub = U + (size_t)bh * 2097152 + (size_t)c * 32768;
  // q @ S  (K = 256)
#pragma unroll
  for (int ks = 0; ks < 8; ++ks) {
    s16x8 qf[4], sf[2];
#pragma unroll
    for (int mi = 0; mi < 4; ++mi)
      qf[mi] = *(const s16x8*)(qbase + (size_t)(mi * 16 + fr) * QKS + ks * 32 + fk);
#pragma unroll
    for (int nj = 0; nj < 2; ++nj)
      sf[nj] = *(const s16x8*)(Ub + (size_t)(wcol + nj * 16 + fr) * 256 + ks * 32 + fk);
#pragma unroll
    for (int mi = 0; mi < 4; ++mi)
#pragma unroll
      for (int nj = 0; nj < 2; ++nj)
        aQS[mi][nj] = __builtin_amdgcn_mfma_f32_16x16x32_bf16(qf[mi], sf[nj],
                                                              aQS[mi][nj], 0, 0, 0);
  }
  // attn @ v  (K = 64)
  const uint16_t* ab = attn + ((size_t)bh * 64 + c) * 4096;
  const uint16_t* vtb = vt + ((size_t)bh * 512 + p * 128) * 4096 + n0;
#pragma unroll
  for (int ks = 0; ks < 2; ++ks) {
    s16x8 af[4], vf[2];
#pragma unroll
    for (int mi = 0; mi < 4; ++mi)
      af[mi] = *(const s16x8*)(ab + (size_t)(mi * 16 + fr) * 64 + ks * 32 + fk);
#pragma unroll
    for (int nj = 0; nj < 2; ++nj)
      vf[nj] = *(const s16x8*)(vtb + (size_t)(wcol + nj * 16 + fr) * 4096 + ks * 32 + fk);
#pragma unroll
    for (int mi = 0; mi < 4; ++mi)
#pragma unroll
      for (int nj = 0; nj < 2; ++nj)
        aPV[mi][nj] = __builtin_amdgcn_mfma_f32_16x16x32_bf16(af[mi], vf[nj],
                                                              aPV[mi][nj], 0, 0, 0);
  }
  const float l2g = log2f(1.f - exp2f(-5.f - (float)h));
  const int rbase = (l >> 4) * 4;
#pragma unroll
  for (int mi = 0; mi < 4; ++mi)
#pragma unroll
    for (int pp = 0; pp < 4; ++pp) {
      const int i = mi * 16 + rbase + pp;
      const float gi = exp2f((float)(i + 1) * l2g);
#pragma unroll
      for (int nj = 0; nj < 2; ++nj) {
        const int wc_ = wcol + nj * 16 + fr;
        const float val = aPV[mi][nj][pp] + gi * aQS[mi][nj][pp];
        o[((size_t)(b * Nn + n0 + i)) * DM + h * DV + p * 128 + wc_] = f2b(val);
      }
    }
}

// ---------------------------------------------------------------------------
// GroupNorm over DV per (b,n,h) + SiLU gate (o bf16), in place into g.
// ---------------------------------------------------------------------------
__global__ __launch_bounds__(256) void gn_gate(const uint16_t* __restrict__ o,
                                               uint16_t* __restrict__ g,
                                               const float* __restrict__ gw) {
  const int bn = blockIdx.x;
  const int tid = threadIdx.x;
  const int h = tid >> 6;
  const int lane = tid & 63;
  const size_t base = (size_t)bn * DM + h * DV + lane * 8;
  uint4 ov4 = *(const uint4*)&o[base];
  float ov[8] = { b2f((uint16_t)ov4.x), b2f((uint16_t)(ov4.x >> 16)),
                  b2f((uint16_t)ov4.y), b2f((uint16_t)(ov4.y >> 16)),
                  b2f((uint16_t)ov4.z), b2f((uint16_t)(ov4.z >> 16)),
                  b2f((uint16_t)ov4.w), b2f((uint16_t)(ov4.w >> 16)) };
  float ss = 0.f;
#pragma unroll
  for (int e = 0; e < 8; ++e) ss += ov[e] * ov[e];
#pragma unroll
  for (int m = 1; m < 64; m <<= 1) ss += __shfl_xor(ss, m, 64);
  const float r = rsqrtf(ss * (1.f / 512.f) + 1e-5f);
  uint4 gv = *(const uint4*)&g[base];
  float gf[8] = { b2f((uint16_t)gv.x), b2f((uint16_t)(gv.x >> 16)),
                  b2f((uint16_t)gv.y), b2f((uint16_t)(gv.y >> 16)),
                  b2f((uint16_t)gv.z), b2f((uint16_t)(gv.z >> 16)),
                  b2f((uint16_t)gv.w), b2f((uint16_t)(gv.w >> 16)) };
  const float* gwp = gw + lane * 8;
  uint16_t res[8];
#pragma unroll
  for (int e = 0; e < 8; ++e) {
    float sil = gf[e] / (1.f + expf(-gf[e]));
    res[e] = f2b(ov[e] * r * gwp[e] * sil);
  }
  uint4 outv;
  outv.x = (uint32_t)res[0] | ((uint32_t)res[1] << 16);
  outv.y = (uint32_t)res[2] | ((uint32_t)res[3] << 16);
  outv.z = (uint32_t)res[4] | ((uint32_t)res[5] << 16);
  outv.w = (uint32_t)res[6] | ((uint32_t)res[7] << 16);
  *(uint4*)&g[base] = outv;
}

// ---------------------------------------------------------------------------
// ws layout (MB), peak 160 (proven size). Overlays, write-before-read ordered:
//   [  0, 32)  xb (dead after fused GEMM)            -> U (scan)
//   [ 32, 64)  qkb   [ 64, 96) vb -> kt[64,80) attn[80,84) wob[84,92)
//   [ 96,128)  gb
//   [128,152)  wall (stacked Wq;Wk;Wv;Wg, dead after fused GEMM)
//                                                    -> vt[128,160)
// o16 (bf16) lives in d_out's first 32MB until gn_gate; final GEMM overwrites
// d_out fp32. Every region fully written before read -> graph-replay safe.
// ---------------------------------------------------------------------------
extern "C" void kernel_launch(void* const* d_in, const int* in_sizes, int n_in,
                              void* d_out, int out_size, void* d_ws, size_t ws_size,
                              hipStream_t stream) {
  const float* x  = (const float*)d_in[0];
  const float* Wq = (const float*)d_in[1];
  const float* Wk = (const float*)d_in[2];
  const float* Wv = (const float*)d_in[3];
  const float* Wg = (const float*)d_in[4];
  const float* Wo = (const float*)d_in[5];
  const float* gw = (const float*)d_in[6];

  char* base = (char*)d_ws;
  uint16_t* xb   = (uint16_t*)(base);                       // [0,32)
  uint16_t* U    = (uint16_t*)(base);                       // overlays xb (scan)
  uint16_t* qkb  = (uint16_t*)(base + ((size_t)32 << 20));  // [32,64)
  uint16_t* vb   = (uint16_t*)(base + ((size_t)64 << 20));  // [64,96)
  uint16_t* kt   = (uint16_t*)(base + ((size_t)64 << 20));  // overlays vb
  uint16_t* attn = (uint16_t*)(base + ((size_t)80 << 20));  // overlays vb
  uint16_t* wob  = (uint16_t*)(base + ((size_t)84 << 20));  // overlays vb
  uint16_t* gb   = (uint16_t*)(base + ((size_t)96 << 20));  // [96,128)
  uint16_t* wall = (uint16_t*)(base + ((size_t)128 << 20)); // [128,152)
  uint16_t* vt   = (uint16_t*)(base + ((size_t)128 << 20)); // overlays wall
  uint16_t* qb   = qkb;                    // q = cols 0-1023
  uint16_t* o16  = (uint16_t*)d_out;       // bf16 o scratch (first 32MB)

  dim3 blk(256), blkG(512);
  // phase 1: conversions + ONE fused GEMM (qk|v|g), 768 blocks
  conv_f2b<<<dim3(8192), blk, 0, stream>>>(x, xb, M * DM / 8);
  conv_w4<<<dim3(6144), blk, 0, stream>>>(Wq, Wk, Wv, Wg, wall);
  gemm8p<true><<<dim3(M/256, 6144/256), blkG, 0, stream>>>(xb, wall, qkb, DM);
  // phase 2: rope; transposes (vb, wall die); attn
  rope_kernel<<<dim3((Bb*Nn*Hh*128)/256), blk, 0, stream>>>(qkb);
  transpose_v<<<dim3(8*8*64), blk, 0, stream>>>(vb, vt);     // vb -> dead
  conv_f2b<<<dim3(2048), blk, 0, stream>>>(Wo, wob, DM * DM / 8);
  transpose_k<<<dim3(8*4*64), blk, 0, stream>>>(qkb, kt);
  attn_mfma<<<dim3(Bb*Hh*NC), blk, 0, stream>>>(qkb, attn);
  // scan: 4 passes of 128 dv cols; U overlays dead xb
  for (int p = 0; p < 4; ++p) {
    chunk_outer<<<dim3(Bb*Hh*NC),  blk, 0, stream>>>(kt, vt, U, p);
    state_scan<<<dim3(1024),       blk, 0, stream>>>(U);
    scan_out<<<dim3(Bb*Hh*NC),     blk, 0, stream>>>(qb, vt, attn, U, o16, p);
  }
  // epilogue
  gn_gate<<<dim3(M), blk, 0, stream>>>(o16, gb, gw);
  gemm8p<false><<<dim3(M/256, DM/256), blkG, 0, stream>>>(gb, wob, (float*)d_out, DM);
}

// Round 15
// 531.847 us; speedup vs baseline: 1.0524x; 1.0248x over previous
//
#include <hip/hip_runtime.h>
#include <hip/hip_bf16.h>
#include <stdint.h>

// Problem constants (MultiScaleRetention: B=2, N=4096, D_MODEL=2048, H=4)
constexpr int Bb   = 2;
constexpr int Nn   = 4096;
constexpr int DM   = 2048;
constexpr int Hh   = 4;
constexpr int DK   = 256;    // KEY_DIM / H
constexpr int DV   = 512;    // D_MODEL / H
constexpr int QKS  = 2048;   // fused q|k row stride (q cols 0-1023, k cols 1024-2047)
constexpr int CH   = 64;     // chunk
constexpr int NC   = Nn / CH;   // 64 chunks
constexpr int M    = Bb * Nn;   // 8192 rows

typedef __attribute__((ext_vector_type(8))) short s16x8;   // 8 bf16 (4 VGPRs)
typedef __attribute__((ext_vector_type(4))) float f32x4;

__device__ __forceinline__ float b2f(uint16_t h) {
  return __uint_as_float(((uint32_t)h) << 16);
}
__device__ __forceinline__ uint16_t f2b(float f) {   // RNE, finite inputs
  uint32_t u = __float_as_uint(f);
  return (uint16_t)((u + 0x7fffu + ((u >> 16) & 1u)) >> 16);
}

// async global->LDS, 16B per lane; LDS dest = wave-uniform base + lane*16
__device__ __forceinline__ void gload16(const void* g, void* l) {
  __builtin_amdgcn_global_load_lds(
      (const __attribute__((address_space(1))) void*)g,
      (__attribute__((address_space(3))) void*)l, 16, 0, 0);
}

#define BARRIER()  asm volatile("s_barrier" ::: "memory")
#define WAITLGKM() do { asm volatile("s_waitcnt lgkmcnt(0)" ::: "memory"); \
                        __builtin_amdgcn_sched_barrier(0); } while (0)
#define VMCNT4()   asm volatile("s_waitcnt vmcnt(4)" ::: "memory")
#define VMCNT0()   asm volatile("s_waitcnt vmcnt(0)" ::: "memory")

// ---------------------------------------------------------------------------
// fp32 -> bf16 bulk convert, 8 elems/thread
// ---------------------------------------------------------------------------
__global__ __launch_bounds__(256) void conv_f2b(const float* __restrict__ s,
                                                uint16_t* __restrict__ d, int n8) {
  int i = blockIdx.x * 256 + threadIdx.x;
  if (i >= n8) return;
  const float4* sp = (const float4*)s;
  float4 a = sp[2 * i], b = sp[2 * i + 1];
  uint4 o;
  o.x = (uint32_t)f2b(a.x) | ((uint32_t)f2b(a.y) << 16);
  o.y = (uint32_t)f2b(a.z) | ((uint32_t)f2b(a.w) << 16);
  o.z = (uint32_t)f2b(b.x) | ((uint32_t)f2b(b.y) << 16);
  o.w = (uint32_t)f2b(b.z) | ((uint32_t)f2b(b.w) << 16);
  ((uint4*)d)[i] = o;
}

// ---------------------------------------------------------------------------
// fused Wq/Wk/Wv/Wg fp32->bf16 into stacked [6144][2048] bf16. 8 elems/thread.
// ---------------------------------------------------------------------------
__global__ __launch_bounds__(256) void conv_w4(const float* __restrict__ Wq,
                                               const float* __restrict__ Wk,
                                               const float* __restrict__ Wv,
                                               const float* __restrict__ Wg,
                                               uint16_t* __restrict__ dst) {
  const int i = blockIdx.x * 256 + threadIdx.x;   // < 1572864
  const float* s; int off;
  if (i < 262144)       { s = Wq; off = i; }
  else if (i < 524288)  { s = Wk; off = i - 262144; }
  else if (i < 1048576) { s = Wv; off = i - 524288; }
  else                  { s = Wg; off = i - 1048576; }
  const float4* sp = (const float4*)s;
  float4 a = sp[2 * off], b = sp[2 * off + 1];
  uint4 o;
  o.x = (uint32_t)f2b(a.x) | ((uint32_t)f2b(a.y) << 16);
  o.y = (uint32_t)f2b(a.z) | ((uint32_t)f2b(a.w) << 16);
  o.z = (uint32_t)f2b(b.x) | ((uint32_t)f2b(b.y) << 16);
  o.w = (uint32_t)f2b(b.z) | ((uint32_t)f2b(b.w) << 16);
  ((uint4*)dst)[i] = o;
}

// ---------------------------------------------------------------------------
// 256x256 8-PHASE GEMM (round-12-proven schedule: MfmaUtil 42%, conflicts 0,
// absmax bit-exact). LDS flattened to one shmem array (identical offsets &
// swizzle algebra: A at [0,32768), B at [32768,65536), per-(slot,khalf)
// 8192-elem regions) so the epilogue can reuse the full 128KB as a C-tile.
// NEW: region-0 (qk) blocks apply RoPE in the epilogue — stash bf16 C-tile
// in dead staging LDS, pair (c, c^128) within the tile (one head's 256 dims
// per tile), identical value chain to the old rope kernel (bf16 in -> fp32
// sincos -> bf16 out, same invf-by-double-exp table) -> absmax bit-exact.
// q tiles (n0<1024) get the 1/16 scale. The standalone rope kernel is gone.
// ---------------------------------------------------------------------------
template<bool OBF>
__global__ __launch_bounds__(512) void gemm8p(const uint16_t* __restrict__ A,
                                              const uint16_t* __restrict__ W,
                                              void* __restrict__ Cout,
                                              int K) {
  __shared__ uint16_t shmem[65536 + 256];   // 128KB staging + 512B invf table
  const int tid = threadIdx.x;
  const int l = tid & 63, w = tid >> 6;
  const int wm = w >> 2, wn = w & 3;
  const int m0 = blockIdx.x * 256, n0 = blockIdx.y * 256;
  const int fr = l & 15;
  const int pu = (((l >> 4) ^ ((fr >> 1) & 3)) * 8);
  const int ssw = ((l & 3) ^ ((l >> 3) & 3)) * 8;
  const uint16_t* aS = A + (size_t)(m0 + w * 32 + (l >> 2)) * K + ssw;
  const uint16_t* wS = W + (size_t)(n0 + w * 32 + (l >> 2)) * K + ssw;

  f32x4 acc[8][4];
#pragma unroll
  for (int mi = 0; mi < 8; ++mi)
#pragma unroll
    for (int nj = 0; nj < 4; ++nj) {
      f32x4 z = {0.f, 0.f, 0.f, 0.f};
      acc[mi][nj] = z;
    }

#define AOFF(S, KH) (((S) * 2 + (KH)) * 8192)
#define BOFF(S, KH) (32768 + ((S) * 2 + (KH)) * 8192)
#define STG_A(S, KH, KT) do {                                                \
    const uint16_t* _p = aS + (size_t)(KT) * 64 + (KH) * 32;                 \
    gload16(_p,                   &shmem[AOFF(S, KH) + (w * 32) * 32]);      \
    gload16(_p + (size_t)16 * K,  &shmem[AOFF(S, KH) + (w * 32 + 16) * 32]); \
  } while (0)
#define STG_B(S, KH, KT) do {                                                \
    const uint16_t* _p = wS + (size_t)(KT) * 64 + (KH) * 32;                 \
    gload16(_p,                   &shmem[BOFF(S, KH) + (w * 32) * 32]);      \
    gload16(_p + (size_t)16 * K,  &shmem[BOFF(S, KH) + (w * 32 + 16) * 32]); \
  } while (0)
#define LDA(S, KH, MI) (*(const s16x8*)&shmem[AOFF(S, KH) + (wm * 128 + (MI) * 16 + fr) * 32 + pu])
#define LDB(S, KH, NJ) (*(const s16x8*)&shmem[BOFF(S, KH) + (wn * 64 + (NJ) * 16 + fr) * 32 + pu])
#define MFMA16(Q) do {                                                       \
    __builtin_amdgcn_s_setprio(1);                                           \
    _Pragma("unroll")                                                        \
    for (int mi = 0; mi < 8; ++mi)                                           \
      acc[mi][2*(Q)] = __builtin_amdgcn_mfma_f32_16x16x32_bf16(              \
          aF[mi], bF0, acc[mi][2*(Q)], 0, 0, 0);                             \
    _Pragma("unroll")                                                        \
    for (int mi = 0; mi < 8; ++mi)                                           \
      acc[mi][2*(Q)+1] = __builtin_amdgcn_mfma_f32_16x16x32_bf16(            \
          aF[mi], bF1, acc[mi][2*(Q)+1], 0, 0, 0);                           \
    __builtin_amdgcn_s_setprio(0);                                           \
  } while (0)

  STG_A(0, 0, 0); STG_B(0, 0, 0); STG_A(0, 1, 0); STG_B(0, 1, 0);
  STG_A(1, 0, 1); STG_B(1, 0, 1);
  VMCNT0();
  BARRIER();

  const int NI = K / 128;
  s16x8 aF[8], bF0, bF1;

  for (int i = 0; i < NI; ++i) {
    const bool nl = (i < NI - 1);
    const size_t t1 = 2 * i + 1, t2 = 2 * i + 2, t3 = 2 * i + 3;
#pragma unroll
    for (int mi = 0; mi < 8; ++mi) aF[mi] = LDA(0, 0, mi);
    bF0 = LDB(0, 0, 0); bF1 = LDB(0, 0, 1);
    STG_A(1, 1, t1);
    BARRIER(); WAITLGKM(); MFMA16(0); BARRIER();
    bF0 = LDB(0, 0, 2); bF1 = LDB(0, 0, 3);
    STG_B(1, 1, t1);
    BARRIER(); WAITLGKM(); MFMA16(1); BARRIER();
#pragma unroll
    for (int mi = 0; mi < 8; ++mi) aF[mi] = LDA(0, 1, mi);
    bF0 = LDB(0, 1, 0); bF1 = LDB(0, 1, 1);
    if (nl) STG_A(0, 0, t2);
    BARRIER(); WAITLGKM(); MFMA16(0); BARRIER();
    bF0 = LDB(0, 1, 2); bF1 = LDB(0, 1, 3);
    if (nl) STG_B(0, 0, t2);
    BARRIER(); WAITLGKM(); MFMA16(1);
    if (nl) VMCNT4(); else VMCNT0();
    BARRIER();
#pragma unroll
    for (int mi = 0; mi < 8; ++mi) aF[mi] = LDA(1, 0, mi);
    bF0 = LDB(1, 0, 0); bF1 = LDB(1, 0, 1);
    if (nl) STG_A(0, 1, t2);
    BARRIER(); WAITLGKM(); MFMA16(0); BARRIER();
    bF0 = LDB(1, 0, 2); bF1 = LDB(1, 0, 3);
    if (nl) STG_B(0, 1, t2);
    BARRIER(); WAITLGKM(); MFMA16(1); BARRIER();
#pragma unroll
    for (int mi = 0; mi < 8; ++mi) aF[mi] = LDA(1, 1, mi);
    bF0 = LDB(1, 1, 0); bF1 = LDB(1, 1, 1);
    if (nl) STG_A(1, 0, t3);
    BARRIER(); WAITLGKM(); MFMA16(0); BARRIER();
    bF0 = LDB(1, 1, 2); bF1 = LDB(1, 1, 3);
    if (nl) STG_B(1, 0, t3);
    BARRIER(); WAITLGKM(); MFMA16(1);
    VMCNT4();
    BARRIER();
  }
#undef STG_A
#undef STG_B
#undef LDA
#undef LDB
#undef MFMA16
#undef AOFF
#undef BOFF

  const int r0 = m0 + wm * 128 + (l >> 4) * 4;
  const int lr0 = wm * 128 + (l >> 4) * 4;       // block-local row base
  const bool doRope = OBF && (n0 < 2048);        // qk region

  if (doRope) {
    // stash bf16 C-tile into dead staging LDS + fill invf table, one sync.
    if (tid < 128)
      ((float*)&shmem[65536])[tid] =
          (float)exp((double)tid * -0.071955784156063938);  // 1e4^(-i/128)
#pragma unroll
    for (int mi = 0; mi < 8; ++mi)
#pragma unroll
      for (int nj = 0; nj < 4; ++nj)
#pragma unroll
        for (int p = 0; p < 4; ++p)
          shmem[(lr0 + mi * 16 + p) * 256 + wn * 64 + fr + nj * 16] =
              f2b(acc[mi][nj][p]);
    __syncthreads();
    const float* invt = (const float*)&shmem[65536];
    const bool isq = (n0 < 1024);
    uint16_t* Cb = (uint16_t*)Cout;              // region 0
#pragma unroll
    for (int mi = 0; mi < 8; ++mi)
#pragma unroll
      for (int nj = 0; nj < 4; ++nj)
#pragma unroll
        for (int p = 0; p < 4; ++p) {
          const int lrow = lr0 + mi * 16 + p;
          const int c = wn * 64 + fr + nj * 16;
          const int grow = m0 + lrow;
          const int n = grow & (Nn - 1);
          const int i2 = c & 127;
          float sn, cs;
          sincosf((float)n * invt[i2], &sn, &cs);
          const float lo = b2f(shmem[lrow * 256 + i2]);
          const float hi = b2f(shmem[lrow * 256 + i2 + 128]);
          float val = (c < 128) ? (lo * cs - hi * sn) : (hi * cs + lo * sn);
          if (isq) val *= 0.0625f;
          Cb[(size_t)grow * 2048 + (n0 & 2047) + c] = f2b(val);
        }
  } else {
#pragma unroll
    for (int mi = 0; mi < 8; ++mi)
#pragma unroll
      for (int nj = 0; nj < 4; ++nj)
#pragma unroll
        for (int p = 0; p < 4; ++p) {
          const int row = r0 + mi * 16 + p;
          if (OBF) {
            uint16_t* Cb = (uint16_t*)Cout + (size_t)(n0 >> 11) * 16777216;
            const int col = (n0 & 2047) + wn * 64 + fr + nj * 16;
            Cb[(size_t)row * 2048 + col] = f2b(acc[mi][nj][p]);
          } else {
            const int col = n0 + wn * 64 + fr + nj * 16;
            ((float*)Cout)[(size_t)row * 2048 + col] = acc[mi][nj][p];
          }
        }
  }
}

// ---------------------------------------------------------------------------
// v transpose: vt[bh][w][n] = v[b][n][h*DV + w].  64x64 LDS tiles.
// ---------------------------------------------------------------------------
__global__ __launch_bounds__(256) void transpose_v(const uint16_t* __restrict__ v,
                                                   uint16_t* __restrict__ vt) {
  const int nt = blockIdx.x & 63;
  const int wt = (blockIdx.x >> 6) & 7;
  const int bh = blockIdx.x >> 9;
  const int b = bh >> 2, h = bh & 3;
  __shared__ uint16_t t[64][72];
  const int lr = threadIdx.x >> 2, lc = (threadIdx.x & 3) * 16;
  const uint16_t* src = v + ((size_t)(b * Nn + nt * 64 + lr)) * DM + h * DV + wt * 64 + lc;
  *(uint4*)&t[lr][lc]     = *(const uint4*)src;
  *(uint4*)&t[lr][lc + 8] = *(const uint4*)(src + 8);
  __syncthreads();
  uint16_t out[16];
#pragma unroll
  for (int e = 0; e < 16; ++e) out[e] = t[lc + e][lr];
  uint16_t* dst = vt + ((size_t)bh * 512 + wt * 64 + lr) * 4096 + nt * 64 + lc;
  *(uint4*)dst       = *(uint4*)&out[0];
  *(uint4*)(dst + 8) = *(uint4*)&out[8];
}

// ---------------------------------------------------------------------------
// k transpose + gamma-scale: kt[bh][d][n] = gamma_h^(63-(n&63)) * k[b][n][d]
// (k = qk cols 1024+h*DK, already rope'd by the GEMM epilogue)
// ---------------------------------------------------------------------------
__global__ __launch_bounds__(256) void transpose_k(const uint16_t* __restrict__ qk,
                                                   uint16_t* __restrict__ kt) {
  const int nt = blockIdx.x & 63;
  const int dt = (blockIdx.x >> 6) & 3;
  const int bh = blockIdx.x >> 8;
  const int b = bh >> 2, h = bh & 3;
  __shared__ uint16_t t[64][72];
  const int lr = threadIdx.x >> 2, lc = (threadIdx.x & 3) * 16;
  const uint16_t* src = qk + ((size_t)(b * Nn + nt * 64 + lr)) * QKS + 1024 + h * DK + dt * 64 + lc;
  *(uint4*)&t[lr][lc]     = *(const uint4*)src;
  *(uint4*)&t[lr][lc + 8] = *(const uint4*)(src + 8);
  __syncthreads();
  const float l2g = log2f(1.f - exp2f(-5.f - (float)h));
  uint16_t out[16];
#pragma unroll
  for (int e = 0; e < 16; ++e)
    out[e] = f2b(b2f(t[lc + e][lr]) * exp2f((float)(63 - (lc + e)) * l2g));
  uint16_t* dst = kt + ((size_t)bh * 256 + dt * 64 + lr) * 4096 + nt * 64 + lc;
  *(uint4*)dst       = *(uint4*)&out[0];
  *(uint4*)(dst + 8) = *(uint4*)&out[8];
}

// ---------------------------------------------------------------------------
// Intra-chunk attention via MFMA: attn[bh][c][i][j] (bf16).
// ---------------------------------------------------------------------------
__global__ __launch_bounds__(256) void attn_mfma(const uint16_t* __restrict__ qk,
                                                 uint16_t* __restrict__ attn) {
  const int c  = blockIdx.x & 63;
  const int bh = blockIdx.x >> 6;
  const int b = bh >> 2, h = bh & 3;
  const int tid = threadIdx.x;
  const int l = tid & 63, w = tid >> 6;
  const int fr = l & 15, fk = (l >> 4) * 8;
  const int n0 = c * CH;
  const uint16_t* qbase = qk + ((size_t)(b * Nn + n0)) * QKS + h * DK;
  const uint16_t* kbase = qbase + 1024;
  f32x4 acc[4];
#pragma unroll
  for (int nj = 0; nj < 4; ++nj) {
    f32x4 z = {0.f, 0.f, 0.f, 0.f};
    acc[nj] = z;
  }
#pragma unroll
  for (int ks = 0; ks < 8; ++ks) {
    s16x8 qf = *(const s16x8*)(qbase + (size_t)(w * 16 + fr) * QKS + ks * 32 + fk);
    s16x8 kf[4];
#pragma unroll
    for (int nj = 0; nj < 4; ++nj)
      kf[nj] = *(const s16x8*)(kbase + (size_t)(nj * 16 + fr) * QKS + ks * 32 + fk);
#pragma unroll
    for (int nj = 0; nj < 4; ++nj)
      acc[nj] = __builtin_amdgcn_mfma_f32_16x16x32_bf16(qf, kf[nj], acc[nj], 0, 0, 0);
  }
  const float l2g = log2f(1.f - exp2f(-5.f - (float)h));
  uint16_t* ab = attn + ((size_t)bh * 64 + c) * 4096;
  const int rbase = (l >> 4) * 4;
#pragma unroll
  for (int pp = 0; pp < 4; ++pp) {
    const int i = w * 16 + rbase + pp;
#pragma unroll
    for (int nj = 0; nj < 4; ++nj) {
      const int j = nj * 16 + fr;
      const float val = (i >= j) ? acc[nj][pp] * exp2f((float)(i - j) * l2g) : 0.f;
      ab[(size_t)i * 64 + j] = f2b(val);
    }
  }
}

// ---------------------------------------------------------------------------
// Kernel A: U_c^T[w,d] = sum_j vt[w,j] * kt[d,j]  (direct-global fragments)
// ---------------------------------------------------------------------------
__global__ __launch_bounds__(256) void chunk_outer(const uint16_t* __restrict__ kt,
                                                   const uint16_t* __restrict__ vt,
                                                   uint16_t* __restrict__ U, int p) {
  const int c  = blockIdx.x & 63;
  const int bh = blockIdx.x >> 6;
  const int tid = threadIdx.x;
  const int l = tid & 63, w = tid >> 6;
  const int wrow = (w >> 1) * 64;     // w' base (M)
  const int wcol = (w & 1) * 128;     // d  base (N)
  const int fr = l & 15, fk = (l >> 4) * 8;
  const int n0 = c * CH;
  const uint16_t* vtb = vt + ((size_t)bh * 512 + p * 128) * 4096 + n0;
  const uint16_t* ktb = kt + ((size_t)bh * 256) * 4096 + n0;
  f32x4 acc[4][8];
#pragma unroll
  for (int mi = 0; mi < 4; ++mi)
#pragma unroll
    for (int nj = 0; nj < 8; ++nj) {
      f32x4 z = {0.f, 0.f, 0.f, 0.f};
      acc[mi][nj] = z;
    }
#pragma unroll
  for (int ks = 0; ks < 2; ++ks) {
    s16x8 af[4], bf8[8];
#pragma unroll
    for (int mi = 0; mi < 4; ++mi)
      af[mi] = *(const s16x8*)(vtb + (size_t)(wrow + mi * 16 + fr) * 4096 + ks * 32 + fk);
#pragma unroll
    for (int nj = 0; nj < 8; ++nj)
      bf8[nj] = *(const s16x8*)(ktb + (size_t)(wcol + nj * 16 + fr) * 4096 + ks * 32 + fk);
#pragma unroll
    for (int mi = 0; mi < 4; ++mi)
#pragma unroll
      for (int nj = 0; nj < 8; ++nj)
        acc[mi][nj] = __builtin_amdgcn_mfma_f32_16x16x32_bf16(af[mi], bf8[nj],
                                                              acc[mi][nj], 0, 0, 0);
  }
  uint16_t* Ub = U + (size_t)bh * 2097152 + (size_t)c * 32768;
  const int rbase = (l >> 4) * 4;
#pragma unroll
  for (int mi = 0; mi < 4; ++mi)
#pragma unroll
    for (int nj = 0; nj < 8; ++nj)
#pragma unroll
      for (int pp = 0; pp < 4; ++pp) {
        const int wq = wrow + mi * 16 + rbase + pp;
        const int d  = wcol + nj * 16 + fr;
        Ub[(size_t)wq * 256 + d] = f2b(acc[mi][nj][pp]);
      }
}

// ---------------------------------------------------------------------------
// Kernel B: in-place state scan (slot c -> S_c), 8-batch load prefetch.
// ---------------------------------------------------------------------------
__global__ __launch_bounds__(256) void state_scan(uint16_t* __restrict__ U) {
  const int gid = blockIdx.x * 256 + threadIdx.x;   // < 8*32768 = 262144
  const int bh = gid >> 15;
  const int e  = gid & 32767;
  const int h  = bh & 3;
  const float l2g = log2f(1.f - exp2f(-5.f - (float)h));
  const float gC = exp2f(64.f * l2g);
  uint16_t* p = U + (size_t)bh * 2097152 + e;
  float S = 0.f;
  for (int cb = 0; cb < 8; ++cb) {
    uint16_t* base = p + (size_t)cb * 8 * 32768;
    float u[8];
#pragma unroll
    for (int ee = 0; ee < 8; ++ee) u[ee] = b2f(base[(size_t)ee * 32768]);
#pragma unroll
    for (int ee = 0; ee < 8; ++ee) {
      base[(size_t)ee * 32768] = f2b(S);
      S = gC * S + u[ee];
    }
  }
}

// ---------------------------------------------------------------------------
// Kernel C: o[i,w] = (attn_c @ v_c)[i,w] + gamma^(i+1)*(q_c @ S_c)[i,w]
// ---------------------------------------------------------------------------
__global__ __launch_bounds__(256) void scan_out(const uint16_t* __restrict__ qk,
                                                const uint16_t* __restrict__ vt,
                                                const uint16_t* __restrict__ attn,
                                                const uint16_t* __restrict__ U,
                                                uint16_t* __restrict__ o, int p) {
  const int c  = blockIdx.x & 63;
  const int bh = blockIdx.x >> 6;
  const int b = bh >> 2, h = bh & 3;
  const int tid = threadIdx.x;
  const int l = tid & 63, wv = tid >> 6;
  const int wcol = wv * 32;                 // output col base (within pass 128)
  const int fr = l & 15, fk = (l >> 4) * 8;
  const int n0 = c * CH;
  f32x4 aQS[4][2], aPV[4][2];
#pragma unroll
  for (int mi = 0; mi < 4; ++mi)
#pragma unroll
    for (int nj = 0; nj < 2; ++nj) {
      f32x4 z = {0.f, 0.f, 0.f, 0.f};
      aQS[mi][nj] = z; aPV[mi][nj] = z;
    }
  const uint16_t* qbase = qk + ((size_t)(b * Nn + n0)) * QKS + h * DK;
  const uint16_t* Ub = U + (size_t)bh * 2097152 + (size_t)c * 32768;
  // q @ S  (K = 256)
#pragma unroll
  for (int ks = 0; ks < 8; ++ks) {
    s16x8 qf[4], sf[2];
#pragma unroll
    for (int mi = 0; mi < 4; ++mi)
      qf[mi] = *(const s16x8*)(qbase + (size_t)(mi * 16 + fr) * QKS + ks * 32 + fk);
#pragma unroll
    for (int nj = 0; nj < 2; ++nj)
      sf[nj] = *(const s16x8*)(Ub + (size_t)(wcol + nj * 16 + fr) * 256 + ks * 32 + fk);
#pragma unroll
    for (int mi = 0; mi < 4; ++mi)
#pragma unroll
      for (int nj = 0; nj < 2; ++nj)
        aQS[mi][nj] = __builtin_amdgcn_mfma_f32_16x16x32_bf16(qf[mi], sf[nj],
                                                              aQS[mi][nj], 0, 0, 0);
  }
  // attn @ v  (K = 64)
  const uint16_t* ab = attn + ((size_t)bh * 64 + c) * 4096;
  const uint16_t* vtb = vt + ((size_t)bh * 512 + p * 128) * 4096 + n0;
#pragma unroll
  for (int ks = 0; ks < 2; ++ks) {
    s16x8 af[4], vf[2];
#pragma unroll
    for (int mi = 0; mi < 4; ++mi)
      af[mi] = *(const s16x8*)(ab + (size_t)(mi * 16 + fr) * 64 + ks * 32 + fk);
#pragma unroll
    for (int nj = 0; nj < 2; ++nj)
      vf[nj] = *(const s16x8*)(vtb + (size_t)(wcol + nj * 16 + fr) * 4096 + ks * 32 + fk);
#pragma unroll
    for (int mi = 0; mi < 4; ++mi)
#pragma unroll
      for (int nj = 0; nj < 2; ++nj)
        aPV[mi][nj] = __builtin_amdgcn_mfma_f32_16x16x32_bf16(af[mi], vf[nj],
                                                              aPV[mi][nj], 0, 0, 0);
  }
  const float l2g = log2f(1.f - exp2f(-5.f - (float)h));
  const int rbase = (l >> 4) * 4;
#pragma unroll
  for (int mi = 0; mi < 4; ++mi)
#pragma unroll
    for (int pp = 0; pp < 4; ++pp) {
      const int i = mi * 16 + rbase + pp;
      const float gi = exp2f((float)(i + 1) * l2g);
#pragma unroll
      for (int nj = 0; nj < 2; ++nj) {
        const int wc_ = wcol + nj * 16 + fr;
        const float val = aPV[mi][nj][pp] + gi * aQS[mi][nj][pp];
        o[((size_t)(b * Nn + n0 + i)) * DM + h * DV + p * 128 + wc_] = f2b(val);
      }
    }
}

// ---------------------------------------------------------------------------
// GroupNorm over DV per (b,n,h) + SiLU gate (o bf16), in place into g.
// ---------------------------------------------------------------------------
__global__ __launch_bounds__(256) void gn_gate(const uint16_t* __restrict__ o,
                                               uint16_t* __restrict__ g,
                                               const float* __restrict__ gw) {
  const int bn = blockIdx.x;
  const int tid = threadIdx.x;
  const int h = tid >> 6;
  const int lane = tid & 63;
  const size_t base = (size_t)bn * DM + h * DV + lane * 8;
  uint4 ov4 = *(const uint4*)&o[base];
  float ov[8] = { b2f((uint16_t)ov4.x), b2f((uint16_t)(ov4.x >> 16)),
                  b2f((uint16_t)ov4.y), b2f((uint16_t)(ov4.y >> 16)),
                  b2f((uint16_t)ov4.z), b2f((uint16_t)(ov4.z >> 16)),
                  b2f((uint16_t)ov4.w), b2f((uint16_t)(ov4.w >> 16)) };
  float ss = 0.f;
#pragma unroll
  for (int e = 0; e < 8; ++e) ss += ov[e] * ov[e];
#pragma unroll
  for (int m = 1; m < 64; m <<= 1) ss += __shfl_xor(ss, m, 64);
  const float r = rsqrtf(ss * (1.f / 512.f) + 1e-5f);
  uint4 gv = *(const uint4*)&g[base];
  float gf[8] = { b2f((uint16_t)gv.x), b2f((uint16_t)(gv.x >> 16)),
                  b2f((uint16_t)gv.y), b2f((uint16_t)(gv.y >> 16)),
                  b2f((uint16_t)gv.z), b2f((uint16_t)(gv.z >> 16)),
                  b2f((uint16_t)gv.w), b2f((uint16_t)(gv.w >> 16)) };
  const float* gwp = gw + lane * 8;
  uint16_t res[8];
#pragma unroll
  for (int e = 0; e < 8; ++e) {
    float sil = gf[e] / (1.f + expf(-gf[e]));
    res[e] = f2b(ov[e] * r * gwp[e] * sil);
  }
  uint4 outv;
  outv.x = (uint32_t)res[0] | ((uint32_t)res[1] << 16);
  outv.y = (uint32_t)res[2] | ((uint32_t)res[3] << 16);
  outv.z = (uint32_t)res[4] | ((uint32_t)res[5] << 16);
  outv.w = (uint32_t)res[6] | ((uint32_t)res[7] << 16);
  *(uint4*)&g[base] = outv;
}

// ---------------------------------------------------------------------------
// ws layout (MB), peak 160 (proven size). Overlays, write-before-read ordered:
//   [  0, 32)  xb (dead after fused GEMM)            -> U (scan)
//   [ 32, 64)  qkb   [ 64, 96) vb -> kt[64,80) attn[80,84) wob[84,92)
//   [ 96,128)  gb
//   [128,152)  wall (stacked Wq;Wk;Wv;Wg, dead after fused GEMM)
//                                                    -> vt[128,160)
// o16 (bf16) lives in d_out's first 32MB until gn_gate; final GEMM overwrites
// d_out fp32. Every region fully written before read -> graph-replay safe.
// ---------------------------------------------------------------------------
extern "C" void kernel_launch(void* const* d_in, const int* in_sizes, int n_in,
                              void* d_out, int out_size, void* d_ws, size_t ws_size,
                              hipStream_t stream) {
  const float* x  = (const float*)d_in[0];
  const float* Wq = (const float*)d_in[1];
  const float* Wk = (const float*)d_in[2];
  const float* Wv = (const float*)d_in[3];
  const float* Wg = (const float*)d_in[4];
  const float* Wo = (const float*)d_in[5];
  const float* gw = (const float*)d_in[6];

  char* base = (char*)d_ws;
  uint16_t* xb   = (uint16_t*)(base);                       // [0,32)
  uint16_t* U    = (uint16_t*)(base);                       // overlays xb (scan)
  uint16_t* qkb  = (uint16_t*)(base + ((size_t)32 << 20));  // [32,64)
  uint16_t* vb   = (uint16_t*)(base + ((size_t)64 << 20));  // [64,96)
  uint16_t* kt   = (uint16_t*)(base + ((size_t)64 << 20));  // overlays vb
  uint16_t* attn = (uint16_t*)(base + ((size_t)80 << 20));  // overlays vb
  uint16_t* wob  = (uint16_t*)(base + ((size_t)84 << 20));  // overlays vb
  uint16_t* gb   = (uint16_t*)(base + ((size_t)96 << 20));  // [96,128)
  uint16_t* wall = (uint16_t*)(base + ((size_t)128 << 20)); // [128,152)
  uint16_t* vt   = (uint16_t*)(base + ((size_t)128 << 20)); // overlays wall
  uint16_t* qb   = qkb;                    // q = cols 0-1023
  uint16_t* o16  = (uint16_t*)d_out;       // bf16 o scratch (first 32MB)

  dim3 blk(256), blkG(512);
  // phase 1: conversions + ONE fused GEMM (qk|v|g, rope fused in epilogue)
  conv_f2b<<<dim3(8192), blk, 0, stream>>>(x, xb, M * DM / 8);
  conv_w4<<<dim3(6144), blk, 0, stream>>>(Wq, Wk, Wv, Wg, wall);
  gemm8p<true><<<dim3(M/256, 6144/256), blkG, 0, stream>>>(xb, wall, qkb, DM);
  // phase 2: transposes (vb, wall die); attn (qk already rope'd)
  transpose_v<<<dim3(8*8*64), blk, 0, stream>>>(vb, vt);     // vb -> dead
  conv_f2b<<<dim3(2048), blk, 0, stream>>>(Wo, wob, DM * DM / 8);
  transpose_k<<<dim3(8*4*64), blk, 0, stream>>>(qkb, kt);
  attn_mfma<<<dim3(Bb*Hh*NC), blk, 0, stream>>>(qkb, attn);
  // scan: 4 passes of 128 dv cols; U overlays dead xb
  for (int p = 0; p < 4; ++p) {
    chunk_outer<<<dim3(Bb*Hh*NC),  blk, 0, stream>>>(kt, vt, U, p);
    state_scan<<<dim3(1024),       blk, 0, stream>>>(U);
    scan_out<<<dim3(Bb*Hh*NC),     blk, 0, stream>>>(qb, vt, attn, U, o16, p);
  }
  // epilogue
  gn_gate<<<dim3(M), blk, 0, stream>>>(o16, gb, gw);
  gemm8p<false><<<dim3(M/256, DM/256), blkG, 0, stream>>>(gb, wob, (float*)d_out, DM);
}

// Round 16
// 515.234 us; speedup vs baseline: 1.0863x; 1.0322x over previous
//
#include <hip/hip_runtime.h>
#include <hip/hip_bf16.h>
#include <stdint.h>

// Problem constants (MultiScaleRetention: B=2, N=4096, D_MODEL=2048, H=4)
constexpr int Bb   = 2;
constexpr int Nn   = 4096;
constexpr int DM   = 2048;
constexpr int Hh   = 4;
constexpr int DK   = 256;    // KEY_DIM / H
constexpr int DV   = 512;    // D_MODEL / H
constexpr int QKS  = 2048;   // fused q|k row stride (q cols 0-1023, k cols 1024-2047)
constexpr int CH   = 64;     // chunk
constexpr int NC   = Nn / CH;   // 64 chunks
constexpr int M    = Bb * Nn;   // 8192 rows

typedef __attribute__((ext_vector_type(8))) short s16x8;   // 8 bf16 (4 VGPRs)
typedef __attribute__((ext_vector_type(4))) float f32x4;

__device__ __forceinline__ float b2f(uint16_t h) {
  return __uint_as_float(((uint32_t)h) << 16);
}
__device__ __forceinline__ uint16_t f2b(float f) {   // RNE, finite inputs
  uint32_t u = __float_as_uint(f);
  return (uint16_t)((u + 0x7fffu + ((u >> 16) & 1u)) >> 16);
}

// async global->LDS, 16B per lane; LDS dest = wave-uniform base + lane*16
__device__ __forceinline__ void gload16(const void* g, void* l) {
  __builtin_amdgcn_global_load_lds(
      (const __attribute__((address_space(1))) void*)g,
      (__attribute__((address_space(3))) void*)l, 16, 0, 0);
}

#define BARRIER()  asm volatile("s_barrier" ::: "memory")
#define WAITLGKM() do { asm volatile("s_waitcnt lgkmcnt(0)" ::: "memory"); \
                        __builtin_amdgcn_sched_barrier(0); } while (0)
#define VMCNT4()   asm volatile("s_waitcnt vmcnt(4)" ::: "memory")
#define VMCNT0()   asm volatile("s_waitcnt vmcnt(0)" ::: "memory")

// ---------------------------------------------------------------------------
// fp32 -> bf16 bulk convert, 8 elems/thread
// ---------------------------------------------------------------------------
__global__ __launch_bounds__(256) void conv_f2b(const float* __restrict__ s,
                                                uint16_t* __restrict__ d, int n8) {
  int i = blockIdx.x * 256 + threadIdx.x;
  if (i >= n8) return;
  const float4* sp = (const float4*)s;
  float4 a = sp[2 * i], b = sp[2 * i + 1];
  uint4 o;
  o.x = (uint32_t)f2b(a.x) | ((uint32_t)f2b(a.y) << 16);
  o.y = (uint32_t)f2b(a.z) | ((uint32_t)f2b(a.w) << 16);
  o.z = (uint32_t)f2b(b.x) | ((uint32_t)f2b(b.y) << 16);
  o.w = (uint32_t)f2b(b.z) | ((uint32_t)f2b(b.w) << 16);
  ((uint4*)d)[i] = o;
}

// ---------------------------------------------------------------------------
// fused Wq/Wk/Wv/Wg fp32->bf16 into stacked [6144][2048] bf16. 8 elems/thread.
// ---------------------------------------------------------------------------
__global__ __launch_bounds__(256) void conv_w4(const float* __restrict__ Wq,
                                               const float* __restrict__ Wk,
                                               const float* __restrict__ Wv,
                                               const float* __restrict__ Wg,
                                               uint16_t* __restrict__ dst) {
  const int i = blockIdx.x * 256 + threadIdx.x;   // < 1572864
  const float* s; int off;
  if (i < 262144)       { s = Wq; off = i; }
  else if (i < 524288)  { s = Wk; off = i - 262144; }
  else if (i < 1048576) { s = Wv; off = i - 524288; }
  else                  { s = Wg; off = i - 1048576; }
  const float4* sp = (const float4*)s;
  float4 a = sp[2 * off], b = sp[2 * off + 1];
  uint4 o;
  o.x = (uint32_t)f2b(a.x) | ((uint32_t)f2b(a.y) << 16);
  o.y = (uint32_t)f2b(a.z) | ((uint32_t)f2b(a.w) << 16);
  o.z = (uint32_t)f2b(b.x) | ((uint32_t)f2b(b.y) << 16);
  o.w = (uint32_t)f2b(b.z) | ((uint32_t)f2b(b.w) << 16);
  ((uint4*)dst)[i] = o;
}

// ---------------------------------------------------------------------------
// 256x256 8-PHASE GEMM (round-12-proven schedule; round-15 RoPE epilogue,
// both absmax-bit-exact). Unchanged this round.
// ---------------------------------------------------------------------------
template<bool OBF>
__global__ __launch_bounds__(512) void gemm8p(const uint16_t* __restrict__ A,
                                              const uint16_t* __restrict__ W,
                                              void* __restrict__ Cout,
                                              int K) {
  __shared__ uint16_t shmem[65536 + 256];   // 128KB staging + 512B invf table
  const int tid = threadIdx.x;
  const int l = tid & 63, w = tid >> 6;
  const int wm = w >> 2, wn = w & 3;
  const int m0 = blockIdx.x * 256, n0 = blockIdx.y * 256;
  const int fr = l & 15;
  const int pu = (((l >> 4) ^ ((fr >> 1) & 3)) * 8);
  const int ssw = ((l & 3) ^ ((l >> 3) & 3)) * 8;
  const uint16_t* aS = A + (size_t)(m0 + w * 32 + (l >> 2)) * K + ssw;
  const uint16_t* wS = W + (size_t)(n0 + w * 32 + (l >> 2)) * K + ssw;

  f32x4 acc[8][4];
#pragma unroll
  for (int mi = 0; mi < 8; ++mi)
#pragma unroll
    for (int nj = 0; nj < 4; ++nj) {
      f32x4 z = {0.f, 0.f, 0.f, 0.f};
      acc[mi][nj] = z;
    }

#define AOFF(S, KH) (((S) * 2 + (KH)) * 8192)
#define BOFF(S, KH) (32768 + ((S) * 2 + (KH)) * 8192)
#define STG_A(S, KH, KT) do {                                                \
    const uint16_t* _p = aS + (size_t)(KT) * 64 + (KH) * 32;                 \
    gload16(_p,                   &shmem[AOFF(S, KH) + (w * 32) * 32]);      \
    gload16(_p + (size_t)16 * K,  &shmem[AOFF(S, KH) + (w * 32 + 16) * 32]); \
  } while (0)
#define STG_B(S, KH, KT) do {                                                \
    const uint16_t* _p = wS + (size_t)(KT) * 64 + (KH) * 32;                 \
    gload16(_p,                   &shmem[BOFF(S, KH) + (w * 32) * 32]);      \
    gload16(_p + (size_t)16 * K,  &shmem[BOFF(S, KH) + (w * 32 + 16) * 32]); \
  } while (0)
#define LDA(S, KH, MI) (*(const s16x8*)&shmem[AOFF(S, KH) + (wm * 128 + (MI) * 16 + fr) * 32 + pu])
#define LDB(S, KH, NJ) (*(const s16x8*)&shmem[BOFF(S, KH) + (wn * 64 + (NJ) * 16 + fr) * 32 + pu])
#define MFMA16(Q) do {                                                       \
    __builtin_amdgcn_s_setprio(1);                                           \
    _Pragma("unroll")                                                        \
    for (int mi = 0; mi < 8; ++mi)                                           \
      acc[mi][2*(Q)] = __builtin_amdgcn_mfma_f32_16x16x32_bf16(              \
          aF[mi], bF0, acc[mi][2*(Q)], 0, 0, 0);                             \
    _Pragma("unroll")                                                        \
    for (int mi = 0; mi < 8; ++mi)                                           \
      acc[mi][2*(Q)+1] = __builtin_amdgcn_mfma_f32_16x16x32_bf16(            \
          aF[mi], bF1, acc[mi][2*(Q)+1], 0, 0, 0);                           \
    __builtin_amdgcn_s_setprio(0);                                           \
  } while (0)

  STG_A(0, 0, 0); STG_B(0, 0, 0); STG_A(0, 1, 0); STG_B(0, 1, 0);
  STG_A(1, 0, 1); STG_B(1, 0, 1);
  VMCNT0();
  BARRIER();

  const int NI = K / 128;
  s16x8 aF[8], bF0, bF1;

  for (int i = 0; i < NI; ++i) {
    const bool nl = (i < NI - 1);
    const size_t t1 = 2 * i + 1, t2 = 2 * i + 2, t3 = 2 * i + 3;
#pragma unroll
    for (int mi = 0; mi < 8; ++mi) aF[mi] = LDA(0, 0, mi);
    bF0 = LDB(0, 0, 0); bF1 = LDB(0, 0, 1);
    STG_A(1, 1, t1);
    BARRIER(); WAITLGKM(); MFMA16(0); BARRIER();
    bF0 = LDB(0, 0, 2); bF1 = LDB(0, 0, 3);
    STG_B(1, 1, t1);
    BARRIER(); WAITLGKM(); MFMA16(1); BARRIER();
#pragma unroll
    for (int mi = 0; mi < 8; ++mi) aF[mi] = LDA(0, 1, mi);
    bF0 = LDB(0, 1, 0); bF1 = LDB(0, 1, 1);
    if (nl) STG_A(0, 0, t2);
    BARRIER(); WAITLGKM(); MFMA16(0); BARRIER();
    bF0 = LDB(0, 1, 2); bF1 = LDB(0, 1, 3);
    if (nl) STG_B(0, 0, t2);
    BARRIER(); WAITLGKM(); MFMA16(1);
    if (nl) VMCNT4(); else VMCNT0();
    BARRIER();
#pragma unroll
    for (int mi = 0; mi < 8; ++mi) aF[mi] = LDA(1, 0, mi);
    bF0 = LDB(1, 0, 0); bF1 = LDB(1, 0, 1);
    if (nl) STG_A(0, 1, t2);
    BARRIER(); WAITLGKM(); MFMA16(0); BARRIER();
    bF0 = LDB(1, 0, 2); bF1 = LDB(1, 0, 3);
    if (nl) STG_B(0, 1, t2);
    BARRIER(); WAITLGKM(); MFMA16(1); BARRIER();
#pragma unroll
    for (int mi = 0; mi < 8; ++mi) aF[mi] = LDA(1, 1, mi);
    bF0 = LDB(1, 1, 0); bF1 = LDB(1, 1, 1);
    if (nl) STG_A(1, 0, t3);
    BARRIER(); WAITLGKM(); MFMA16(0); BARRIER();
    bF0 = LDB(1, 1, 2); bF1 = LDB(1, 1, 3);
    if (nl) STG_B(1, 0, t3);
    BARRIER(); WAITLGKM(); MFMA16(1);
    VMCNT4();
    BARRIER();
  }
#undef STG_A
#undef STG_B
#undef LDA
#undef LDB
#undef MFMA16
#undef AOFF
#undef BOFF

  const int r0 = m0 + wm * 128 + (l >> 4) * 4;
  const int lr0 = wm * 128 + (l >> 4) * 4;       // block-local row base
  const bool doRope = OBF && (n0 < 2048);        // qk region

  if (doRope) {
    if (tid < 128)
      ((float*)&shmem[65536])[tid] =
          (float)exp((double)tid * -0.071955784156063938);  // 1e4^(-i/128)
#pragma unroll
    for (int mi = 0; mi < 8; ++mi)
#pragma unroll
      for (int nj = 0; nj < 4; ++nj)
#pragma unroll
        for (int p = 0; p < 4; ++p)
          shmem[(lr0 + mi * 16 + p) * 256 + wn * 64 + fr + nj * 16] =
              f2b(acc[mi][nj][p]);
    __syncthreads();
    const float* invt = (const float*)&shmem[65536];
    const bool isq = (n0 < 1024);
    uint16_t* Cb = (uint16_t*)Cout;              // region 0
#pragma unroll
    for (int mi = 0; mi < 8; ++mi)
#pragma unroll
      for (int nj = 0; nj < 4; ++nj)
#pragma unroll
        for (int p = 0; p < 4; ++p) {
          const int lrow = lr0 + mi * 16 + p;
          const int c = wn * 64 + fr + nj * 16;
          const int grow = m0 + lrow;
          const int n = grow & (Nn - 1);
          const int i2 = c & 127;
          float sn, cs;
          sincosf((float)n * invt[i2], &sn, &cs);
          const float lo = b2f(shmem[lrow * 256 + i2]);
          const float hi = b2f(shmem[lrow * 256 + i2 + 128]);
          float val = (c < 128) ? (lo * cs - hi * sn) : (hi * cs + lo * sn);
          if (isq) val *= 0.0625f;
          Cb[(size_t)grow * 2048 + (n0 & 2047) + c] = f2b(val);
        }
  } else {
#pragma unroll
    for (int mi = 0; mi < 8; ++mi)
#pragma unroll
      for (int nj = 0; nj < 4; ++nj)
#pragma unroll
        for (int p = 0; p < 4; ++p) {
          const int row = r0 + mi * 16 + p;
          if (OBF) {
            uint16_t* Cb = (uint16_t*)Cout + (size_t)(n0 >> 11) * 16777216;
            const int col = (n0 & 2047) + wn * 64 + fr + nj * 16;
            Cb[(size_t)row * 2048 + col] = f2b(acc[mi][nj][p]);
          } else {
            const int col = n0 + wn * 64 + fr + nj * 16;
            ((float*)Cout)[(size_t)row * 2048 + col] = acc[mi][nj][p];
          }
        }
  }
}

// ---------------------------------------------------------------------------
// v transpose: vt[bh][w][n] = v[b][n][h*DV + w].  64x64 LDS tiles.
// ---------------------------------------------------------------------------
__global__ __launch_bounds__(256) void transpose_v(const uint16_t* __restrict__ v,
                                                   uint16_t* __restrict__ vt) {
  const int nt = blockIdx.x & 63;
  const int wt = (blockIdx.x >> 6) & 7;
  const int bh = blockIdx.x >> 9;
  const int b = bh >> 2, h = bh & 3;
  __shared__ uint16_t t[64][72];
  const int lr = threadIdx.x >> 2, lc = (threadIdx.x & 3) * 16;
  const uint16_t* src = v + ((size_t)(b * Nn + nt * 64 + lr)) * DM + h * DV + wt * 64 + lc;
  *(uint4*)&t[lr][lc]     = *(const uint4*)src;
  *(uint4*)&t[lr][lc + 8] = *(const uint4*)(src + 8);
  __syncthreads();
  uint16_t out[16];
#pragma unroll
  for (int e = 0; e < 16; ++e) out[e] = t[lc + e][lr];
  uint16_t* dst = vt + ((size_t)bh * 512 + wt * 64 + lr) * 4096 + nt * 64 + lc;
  *(uint4*)dst       = *(uint4*)&out[0];
  *(uint4*)(dst + 8) = *(uint4*)&out[8];
}

// ---------------------------------------------------------------------------
// k transpose + gamma-scale: kt[bh][d][n] = gamma_h^(63-(n&63)) * k[b][n][d]
// ---------------------------------------------------------------------------
__global__ __launch_bounds__(256) void transpose_k(const uint16_t* __restrict__ qk,
                                                   uint16_t* __restrict__ kt) {
  const int nt = blockIdx.x & 63;
  const int dt = (blockIdx.x >> 6) & 3;
  const int bh = blockIdx.x >> 8;
  const int b = bh >> 2, h = bh & 3;
  __shared__ uint16_t t[64][72];
  const int lr = threadIdx.x >> 2, lc = (threadIdx.x & 3) * 16;
  const uint16_t* src = qk + ((size_t)(b * Nn + nt * 64 + lr)) * QKS + 1024 + h * DK + dt * 64 + lc;
  *(uint4*)&t[lr][lc]     = *(const uint4*)src;
  *(uint4*)&t[lr][lc + 8] = *(const uint4*)(src + 8);
  __syncthreads();
  const float l2g = log2f(1.f - exp2f(-5.f - (float)h));
  uint16_t out[16];
#pragma unroll
  for (int e = 0; e < 16; ++e)
    out[e] = f2b(b2f(t[lc + e][lr]) * exp2f((float)(63 - (lc + e)) * l2g));
  uint16_t* dst = kt + ((size_t)bh * 256 + dt * 64 + lr) * 4096 + nt * 64 + lc;
  *(uint4*)dst       = *(uint4*)&out[0];
  *(uint4*)(dst + 8) = *(uint4*)&out[8];
}

// ---------------------------------------------------------------------------
// Intra-chunk attention via MFMA: attn[bh][c][i][j] (bf16).
// ---------------------------------------------------------------------------
__global__ __launch_bounds__(256) void attn_mfma(const uint16_t* __restrict__ qk,
                                                 uint16_t* __restrict__ attn) {
  const int c  = blockIdx.x & 63;
  const int bh = blockIdx.x >> 6;
  const int b = bh >> 2, h = bh & 3;
  const int tid = threadIdx.x;
  const int l = tid & 63, w = tid >> 6;
  const int fr = l & 15, fk = (l >> 4) * 8;
  const int n0 = c * CH;
  const uint16_t* qbase = qk + ((size_t)(b * Nn + n0)) * QKS + h * DK;
  const uint16_t* kbase = qbase + 1024;
  f32x4 acc[4];
#pragma unroll
  for (int nj = 0; nj < 4; ++nj) {
    f32x4 z = {0.f, 0.f, 0.f, 0.f};
    acc[nj] = z;
  }
#pragma unroll
  for (int ks = 0; ks < 8; ++ks) {
    s16x8 qf = *(const s16x8*)(qbase + (size_t)(w * 16 + fr) * QKS + ks * 32 + fk);
    s16x8 kf[4];
#pragma unroll
    for (int nj = 0; nj < 4; ++nj)
      kf[nj] = *(const s16x8*)(kbase + (size_t)(nj * 16 + fr) * QKS + ks * 32 + fk);
#pragma unroll
    for (int nj = 0; nj < 4; ++nj)
      acc[nj] = __builtin_amdgcn_mfma_f32_16x16x32_bf16(qf, kf[nj], acc[nj], 0, 0, 0);
  }
  const float l2g = log2f(1.f - exp2f(-5.f - (float)h));
  uint16_t* ab = attn + ((size_t)bh * 64 + c) * 4096;
  const int rbase = (l >> 4) * 4;
#pragma unroll
  for (int pp = 0; pp < 4; ++pp) {
    const int i = w * 16 + rbase + pp;
#pragma unroll
    for (int nj = 0; nj < 4; ++nj) {
      const int j = nj * 16 + fr;
      const float val = (i >= j) ? acc[nj][pp] * exp2f((float)(i - j) * l2g) : 0.f;
      ab[(size_t)i * 64 + j] = f2b(val);
    }
  }
}

// ---------------------------------------------------------------------------
// Kernel A: U_c^T[w,d] = sum_j vt[w,j] * kt[d,j]. MERGED: grid 1024 covers
// two dv slices (p = pbase + blockIdx.x>>9, U half selected to match).
// Per-block math identical to round-15 (pure re-index) -> absmax bit-exact.
// ---------------------------------------------------------------------------
__global__ __launch_bounds__(256) void chunk_outer(const uint16_t* __restrict__ kt,
                                                   const uint16_t* __restrict__ vt,
                                                   uint16_t* __restrict__ U0,
                                                   uint16_t* __restrict__ U1,
                                                   int pbase) {
  const int sub = blockIdx.x >> 9;
  uint16_t* U = sub ? U1 : U0;
  const int p = pbase + sub;
  const int c  = blockIdx.x & 63;
  const int bh = (blockIdx.x >> 6) & 7;
  const int tid = threadIdx.x;
  const int l = tid & 63, w = tid >> 6;
  const int wrow = (w >> 1) * 64;     // w' base (M)
  const int wcol = (w & 1) * 128;     // d  base (N)
  const int fr = l & 15, fk = (l >> 4) * 8;
  const int n0 = c * CH;
  const uint16_t* vtb = vt + ((size_t)bh * 512 + p * 128) * 4096 + n0;
  const uint16_t* ktb = kt + ((size_t)bh * 256) * 4096 + n0;
  f32x4 acc[4][8];
#pragma unroll
  for (int mi = 0; mi < 4; ++mi)
#pragma unroll
    for (int nj = 0; nj < 8; ++nj) {
      f32x4 z = {0.f, 0.f, 0.f, 0.f};
      acc[mi][nj] = z;
    }
#pragma unroll
  for (int ks = 0; ks < 2; ++ks) {
    s16x8 af[4], bf8[8];
#pragma unroll
    for (int mi = 0; mi < 4; ++mi)
      af[mi] = *(const s16x8*)(vtb + (size_t)(wrow + mi * 16 + fr) * 4096 + ks * 32 + fk);
#pragma unroll
    for (int nj = 0; nj < 8; ++nj)
      bf8[nj] = *(const s16x8*)(ktb + (size_t)(wcol + nj * 16 + fr) * 4096 + ks * 32 + fk);
#pragma unroll
    for (int mi = 0; mi < 4; ++mi)
#pragma unroll
      for (int nj = 0; nj < 8; ++nj)
        acc[mi][nj] = __builtin_amdgcn_mfma_f32_16x16x32_bf16(af[mi], bf8[nj],
                                                              acc[mi][nj], 0, 0, 0);
  }
  uint16_t* Ub = U + (size_t)bh * 2097152 + (size_t)c * 32768;
  const int rbase = (l >> 4) * 4;
#pragma unroll
  for (int mi = 0; mi < 4; ++mi)
#pragma unroll
    for (int nj = 0; nj < 8; ++nj)
#pragma unroll
      for (int pp = 0; pp < 4; ++pp) {
        const int wq = wrow + mi * 16 + rbase + pp;
        const int d  = wcol + nj * 16 + fr;
        Ub[(size_t)wq * 256 + d] = f2b(acc[mi][nj][pp]);
      }
}

// ---------------------------------------------------------------------------
// Kernel B: in-place state scan. MERGED: grid 2048 covers both U halves
// (first 1024 blocks -> U0, rest -> U1). Same per-element math.
// ---------------------------------------------------------------------------
__global__ __launch_bounds__(256) void state_scan(uint16_t* __restrict__ U0,
                                                  uint16_t* __restrict__ U1) {
  uint16_t* U = (blockIdx.x >= 1024) ? U1 : U0;
  const int gid = (blockIdx.x & 1023) * 256 + threadIdx.x;  // < 262144
  const int bh = gid >> 15;
  const int e  = gid & 32767;
  const int h  = bh & 3;
  const float l2g = log2f(1.f - exp2f(-5.f - (float)h));
  const float gC = exp2f(64.f * l2g);
  uint16_t* p = U + (size_t)bh * 2097152 + e;
  float S = 0.f;
  for (int cb = 0; cb < 8; ++cb) {
    uint16_t* base = p + (size_t)cb * 8 * 32768;
    float u[8];
#pragma unroll
    for (int ee = 0; ee < 8; ++ee) u[ee] = b2f(base[(size_t)ee * 32768]);
#pragma unroll
    for (int ee = 0; ee < 8; ++ee) {
      base[(size_t)ee * 32768] = f2b(S);
      S = gC * S + u[ee];
    }
  }
}

// ---------------------------------------------------------------------------
// Kernel C: o[i,w] = (attn_c @ v_c)[i,w] + gamma^(i+1)*(q_c @ S_c)[i,w]
// MERGED: grid 1024, same (p, U) selection as chunk_outer.
// ---------------------------------------------------------------------------
__global__ __launch_bounds__(256) void scan_out(const uint16_t* __restrict__ qk,
                                                const uint16_t* __restrict__ vt,
                                                const uint16_t* __restrict__ attn,
                                                const uint16_t* __restrict__ U0,
                                                const uint16_t* __restrict__ U1,
                                                uint16_t* __restrict__ o, int pbase) {
  const int sub = blockIdx.x >> 9;
  const uint16_t* U = sub ? U1 : U0;
  const int p = pbase + sub;
  const int c  = blockIdx.x & 63;
  const int bh = (blockIdx.x >> 6) & 7;
  const int b = bh >> 2, h = bh & 3;
  const int tid = threadIdx.x;
  const int l = tid & 63, wv = tid >> 6;
  const int wcol = wv * 32;                 // output col base (within pass 128)
  const int fr = l & 15, fk = (l >> 4) * 8;
  const int n0 = c * CH;
  f32x4 aQS[4][2], aPV[4][2];
#pragma unroll
  for (int mi = 0; mi < 4; ++mi)
#pragma unroll
    for (int nj = 0; nj < 2; ++nj) {
      f32x4 z = {0.f, 0.f, 0.f, 0.f};
      aQS[mi][nj] = z; aPV[mi][nj] = z;
    }
  const uint16_t* qbase = qk + ((size_t)(b * Nn + n0)) * QKS + h * DK;
  const uint16_t* Ub = U + (size_t)bh * 2097152 + (size_t)c * 32768;
  // q @ S  (K = 256)
#pragma unroll
  for (int ks = 0; ks < 8; ++ks) {
    s16x8 qf[4], sf[2];
#pragma unroll
    for (int mi = 0; mi < 4; ++mi)
      qf[mi] = *(const s16x8*)(qbase + (size_t)(mi * 16 + fr) * QKS + ks * 32 + fk);
#pragma unroll
    for (int nj = 0; nj < 2; ++nj)
      sf[nj] = *(const s16x8*)(Ub + (size_t)(wcol + nj * 16 + fr) * 256 + ks * 32 + fk);
#pragma unroll
    for (int mi = 0; mi < 4; ++mi)
#pragma unroll
      for (int nj = 0; nj < 2; ++nj)
        aQS[mi][nj] = __builtin_amdgcn_mfma_f32_16x16x32_bf16(qf[mi], sf[nj],
                                                              aQS[mi][nj], 0, 0, 0);
  }
  // attn @ v  (K = 64)
  const uint16_t* ab = attn + ((size_t)bh * 64 + c) * 4096;
  const uint16_t* vtb = vt + ((size_t)bh * 512 + p * 128) * 4096 + n0;
#pragma unroll
  for (int ks = 0; ks < 2; ++ks) {
    s16x8 af[4], vf[2];
#pragma unroll
    for (int mi = 0; mi < 4; ++mi)
      af[mi] = *(const s16x8*)(ab + (size_t)(mi * 16 + fr) * 64 + ks * 32 + fk);
#pragma unroll
    for (int nj = 0; nj < 2; ++nj)
      vf[nj] = *(const s16x8*)(vtb + (size_t)(wcol + nj * 16 + fr) * 4096 + ks * 32 + fk);
#pragma unroll
    for (int mi = 0; mi < 4; ++mi)
#pragma unroll
      for (int nj = 0; nj < 2; ++nj)
        aPV[mi][nj] = __builtin_amdgcn_mfma_f32_16x16x32_bf16(af[mi], vf[nj],
                                                              aPV[mi][nj], 0, 0, 0);
  }
  const float l2g = log2f(1.f - exp2f(-5.f - (float)h));
  const int rbase = (l >> 4) * 4;
#pragma unroll
  for (int mi = 0; mi < 4; ++mi)
#pragma unroll
    for (int pp = 0; pp < 4; ++pp) {
      const int i = mi * 16 + rbase + pp;
      const float gi = exp2f((float)(i + 1) * l2g);
#pragma unroll
      for (int nj = 0; nj < 2; ++nj) {
        const int wc_ = wcol + nj * 16 + fr;
        const float val = aPV[mi][nj][pp] + gi * aQS[mi][nj][pp];
        o[((size_t)(b * Nn + n0 + i)) * DM + h * DV + p * 128 + wc_] = f2b(val);
      }
    }
}

// ---------------------------------------------------------------------------
// GroupNorm over DV per (b,n,h) + SiLU gate (o bf16), in place into g.
// ---------------------------------------------------------------------------
__global__ __launch_bounds__(256) void gn_gate(const uint16_t* __restrict__ o,
                                               uint16_t* __restrict__ g,
                                               const float* __restrict__ gw) {
  const int bn = blockIdx.x;
  const int tid = threadIdx.x;
  const int h = tid >> 6;
  const int lane = tid & 63;
  const size_t base = (size_t)bn * DM + h * DV + lane * 8;
  uint4 ov4 = *(const uint4*)&o[base];
  float ov[8] = { b2f((uint16_t)ov4.x), b2f((uint16_t)(ov4.x >> 16)),
                  b2f((uint16_t)ov4.y), b2f((uint16_t)(ov4.y >> 16)),
                  b2f((uint16_t)ov4.z), b2f((uint16_t)(ov4.z >> 16)),
                  b2f((uint16_t)ov4.w), b2f((uint16_t)(ov4.w >> 16)) };
  float ss = 0.f;
#pragma unroll
  for (int e = 0; e < 8; ++e) ss += ov[e] * ov[e];
#pragma unroll
  for (int m = 1; m < 64; m <<= 1) ss += __shfl_xor(ss, m, 64);
  const float r = rsqrtf(ss * (1.f / 512.f) + 1e-5f);
  uint4 gv = *(const uint4*)&g[base];
  float gf[8] = { b2f((uint16_t)gv.x), b2f((uint16_t)(gv.x >> 16)),
                  b2f((uint16_t)gv.y), b2f((uint16_t)(gv.y >> 16)),
                  b2f((uint16_t)gv.z), b2f((uint16_t)(gv.z >> 16)),
                  b2f((uint16_t)gv.w), b2f((uint16_t)(gv.w >> 16)) };
  const float* gwp = gw + lane * 8;
  uint16_t res[8];
#pragma unroll
  for (int e = 0; e < 8; ++e) {
    float sil = gf[e] / (1.f + expf(-gf[e]));
    res[e] = f2b(ov[e] * r * gwp[e] * sil);
  }
  uint4 outv;
  outv.x = (uint32_t)res[0] | ((uint32_t)res[1] << 16);
  outv.y = (uint32_t)res[2] | ((uint32_t)res[3] << 16);
  outv.z = (uint32_t)res[4] | ((uint32_t)res[5] << 16);
  outv.w = (uint32_t)res[6] | ((uint32_t)res[7] << 16);
  *(uint4*)&g[base] = outv;
}

// ---------------------------------------------------------------------------
// ws layout (MB), peak 160 (proven size). Overlays, write-before-read ordered:
//   [  0, 32)  xb (dead after fused GEMM)            -> U0 (scan)
//   [ 32, 64)  qkb   [ 64, 96) vb -> kt[64,80) attn[80,84) wob[84,92)
//   [ 96,128)  gb
//   [128,152)  wall (dead after fused GEMM)          -> vt[128,160)
// d_out (64MB): o16 bf16 in [0,32); U1 scratch in [32,64) during the scan
// (fully written by chunk_outer before read; final GEMM overwrites ALL of
// d_out fp32). Every region fully written before read -> graph-replay safe.
// ---------------------------------------------------------------------------
extern "C" void kernel_launch(void* const* d_in, const int* in_sizes, int n_in,
                              void* d_out, int out_size, void* d_ws, size_t ws_size,
                              hipStream_t stream) {
  const float* x  = (const float*)d_in[0];
  const float* Wq = (const float*)d_in[1];
  const float* Wk = (const float*)d_in[2];
  const float* Wv = (const float*)d_in[3];
  const float* Wg = (const float*)d_in[4];
  const float* Wo = (const float*)d_in[5];
  const float* gw = (const float*)d_in[6];

  char* base = (char*)d_ws;
  uint16_t* xb   = (uint16_t*)(base);                       // [0,32)
  uint16_t* U0   = (uint16_t*)(base);                       // overlays xb (scan)
  uint16_t* qkb  = (uint16_t*)(base + ((size_t)32 << 20));  // [32,64)
  uint16_t* vb   = (uint16_t*)(base + ((size_t)64 << 20));  // [64,96)
  uint16_t* kt   = (uint16_t*)(base + ((size_t)64 << 20));  // overlays vb
  uint16_t* attn = (uint16_t*)(base + ((size_t)80 << 20));  // overlays vb
  uint16_t* wob  = (uint16_t*)(base + ((size_t)84 << 20));  // overlays vb
  uint16_t* gb   = (uint16_t*)(base + ((size_t)96 << 20));  // [96,128)
  uint16_t* wall = (uint16_t*)(base + ((size_t)128 << 20)); // [128,152)
  uint16_t* vt   = (uint16_t*)(base + ((size_t)128 << 20)); // overlays wall
  uint16_t* qb   = qkb;                    // q = cols 0-1023
  uint16_t* o16  = (uint16_t*)d_out;       // bf16 o scratch (d_out [0,32MB))
  uint16_t* U1   = (uint16_t*)d_out + 16777216;  // d_out [32,64MB) scratch

  dim3 blk(256), blkG(512);
  // phase 1: conversions + ONE fused GEMM (qk|v|g, rope fused in epilogue)
  conv_f2b<<<dim3(8192), blk, 0, stream>>>(x, xb, M * DM / 8);
  conv_w4<<<dim3(6144), blk, 0, stream>>>(Wq, Wk, Wv, Wg, wall);
  gemm8p<true><<<dim3(M/256, 6144/256), blkG, 0, stream>>>(xb, wall, qkb, DM);
  // phase 2: transposes (vb, wall die); attn (qk already rope'd)
  transpose_v<<<dim3(8*8*64), blk, 0, stream>>>(vb, vt);     // vb -> dead
  conv_f2b<<<dim3(2048), blk, 0, stream>>>(Wo, wob, DM * DM / 8);
  transpose_k<<<dim3(8*4*64), blk, 0, stream>>>(qkb, kt);
  attn_mfma<<<dim3(Bb*Hh*NC), blk, 0, stream>>>(qkb, attn);
  // scan: 2 super-passes of 256 dv cols (2 slices each); U0 overlays dead xb,
  // U1 lives in d_out's upper half.
  for (int s = 0; s < 2; ++s) {
    chunk_outer<<<dim3(1024), blk, 0, stream>>>(kt, vt, U0, U1, 2 * s);
    state_scan<<<dim3(2048),  blk, 0, stream>>>(U0, U1);
    scan_out<<<dim3(1024),    blk, 0, stream>>>(qb, vt, attn, U0, U1, o16, 2 * s);
  }
  // epilogue
  gn_gate<<<dim3(M), blk, 0, stream>>>(o16, gb, gw);
  gemm8p<false><<<dim3(M/256, DM/256), blkG, 0, stream>>>(gb, wob, (float*)d_out, DM);
}

// Round 17
// 514.862 us; speedup vs baseline: 1.0871x; 1.0007x over previous
//
#include <hip/hip_runtime.h>
#include <hip/hip_bf16.h>
#include <stdint.h>

// Problem constants (MultiScaleRetention: B=2, N=4096, D_MODEL=2048, H=4)
constexpr int Bb   = 2;
constexpr int Nn   = 4096;
constexpr int DM   = 2048;
constexpr int Hh   = 4;
constexpr int DK   = 256;    // KEY_DIM / H
constexpr int DV   = 512;    // D_MODEL / H
constexpr int QKS  = 2048;   // fused q|k row stride (q cols 0-1023, k cols 1024-2047)
constexpr int CH   = 64;     // chunk
constexpr int NC   = Nn / CH;   // 64 chunks
constexpr int M    = Bb * Nn;   // 8192 rows

typedef __attribute__((ext_vector_type(8))) short s16x8;   // 8 bf16 (4 VGPRs)
typedef __attribute__((ext_vector_type(4))) float f32x4;

__device__ __forceinline__ float b2f(uint16_t h) {
  return __uint_as_float(((uint32_t)h) << 16);
}
__device__ __forceinline__ uint16_t f2b(float f) {   // RNE, finite inputs
  uint32_t u = __float_as_uint(f);
  return (uint16_t)((u + 0x7fffu + ((u >> 16) & 1u)) >> 16);
}

// async global->LDS, 16B per lane; LDS dest = wave-uniform base + lane*16
__device__ __forceinline__ void gload16(const void* g, void* l) {
  __builtin_amdgcn_global_load_lds(
      (const __attribute__((address_space(1))) void*)g,
      (__attribute__((address_space(3))) void*)l, 16, 0, 0);
}

#define BARRIER()  asm volatile("s_barrier" ::: "memory")
#define WAITLGKM() do { asm volatile("s_waitcnt lgkmcnt(0)" ::: "memory"); \
                        __builtin_amdgcn_sched_barrier(0); } while (0)
#define VMCNT4()   asm volatile("s_waitcnt vmcnt(4)" ::: "memory")
#define VMCNT0()   asm volatile("s_waitcnt vmcnt(0)" ::: "memory")

// ---------------------------------------------------------------------------
// helper bodies (shared by merged dispatchers) — byte-identical math to the
// round-16 standalone kernels.
// ---------------------------------------------------------------------------
__device__ __forceinline__ void conv_body(const float* __restrict__ s,
                                          uint16_t* __restrict__ d, int i, int n8) {
  if (i >= n8) return;
  const float4* sp = (const float4*)s;
  float4 a = sp[2 * i], b = sp[2 * i + 1];
  uint4 o;
  o.x = (uint32_t)f2b(a.x) | ((uint32_t)f2b(a.y) << 16);
  o.y = (uint32_t)f2b(a.z) | ((uint32_t)f2b(a.w) << 16);
  o.z = (uint32_t)f2b(b.x) | ((uint32_t)f2b(b.y) << 16);
  o.w = (uint32_t)f2b(b.z) | ((uint32_t)f2b(b.w) << 16);
  ((uint4*)d)[i] = o;
}

// ---------------------------------------------------------------------------
// MERGED conv_all: blocks [0,8192) convert x -> xb; [8192,14336) convert
// Wq/Wk/Wv/Wg -> wall (stacked [6144][2048]). Independent writes; math
// identical to round-16's conv_f2b / conv_w4.
// ---------------------------------------------------------------------------
__global__ __launch_bounds__(256) void conv_all(const float* __restrict__ x,
                                                const float* __restrict__ Wq,
                                                const float* __restrict__ Wk,
                                                const float* __restrict__ Wv,
                                                const float* __restrict__ Wg,
                                                uint16_t* __restrict__ xb,
                                                uint16_t* __restrict__ wall) {
  const int bid = blockIdx.x;
  if (bid < 8192) {
    conv_body(x, xb, bid * 256 + threadIdx.x, M * DM / 8);
  } else {
    const int i = (bid - 8192) * 256 + threadIdx.x;   // < 1572864
    const float* s; int off;
    if (i < 262144)       { s = Wq; off = i; }
    else if (i < 524288)  { s = Wk; off = i - 262144; }
    else if (i < 1048576) { s = Wv; off = i - 524288; }
    else                  { s = Wg; off = i - 1048576; }
    const float4* sp = (const float4*)s;
    float4 a = sp[2 * off], b = sp[2 * off + 1];
    uint4 o;
    o.x = (uint32_t)f2b(a.x) | ((uint32_t)f2b(a.y) << 16);
    o.y = (uint32_t)f2b(a.z) | ((uint32_t)f2b(a.w) << 16);
    o.z = (uint32_t)f2b(b.x) | ((uint32_t)f2b(b.y) << 16);
    o.w = (uint32_t)f2b(b.z) | ((uint32_t)f2b(b.w) << 16);
    ((uint4*)wall)[i] = o;
  }
}

// ---------------------------------------------------------------------------
// 256x256 8-PHASE GEMM (round-12-proven schedule; round-15 RoPE epilogue,
// both absmax-bit-exact). Unchanged this round.
// ---------------------------------------------------------------------------
template<bool OBF>
__global__ __launch_bounds__(512) void gemm8p(const uint16_t* __restrict__ A,
                                              const uint16_t* __restrict__ W,
                                              void* __restrict__ Cout,
                                              int K) {
  __shared__ uint16_t shmem[65536 + 256];   // 128KB staging + 512B invf table
  const int tid = threadIdx.x;
  const int l = tid & 63, w = tid >> 6;
  const int wm = w >> 2, wn = w & 3;
  const int m0 = blockIdx.x * 256, n0 = blockIdx.y * 256;
  const int fr = l & 15;
  const int pu = (((l >> 4) ^ ((fr >> 1) & 3)) * 8);
  const int ssw = ((l & 3) ^ ((l >> 3) & 3)) * 8;
  const uint16_t* aS = A + (size_t)(m0 + w * 32 + (l >> 2)) * K + ssw;
  const uint16_t* wS = W + (size_t)(n0 + w * 32 + (l >> 2)) * K + ssw;

  f32x4 acc[8][4];
#pragma unroll
  for (int mi = 0; mi < 8; ++mi)
#pragma unroll
    for (int nj = 0; nj < 4; ++nj) {
      f32x4 z = {0.f, 0.f, 0.f, 0.f};
      acc[mi][nj] = z;
    }

#define AOFF(S, KH) (((S) * 2 + (KH)) * 8192)
#define BOFF(S, KH) (32768 + ((S) * 2 + (KH)) * 8192)
#define STG_A(S, KH, KT) do {                                                \
    const uint16_t* _p = aS + (size_t)(KT) * 64 + (KH) * 32;                 \
    gload16(_p,                   &shmem[AOFF(S, KH) + (w * 32) * 32]);      \
    gload16(_p + (size_t)16 * K,  &shmem[AOFF(S, KH) + (w * 32 + 16) * 32]); \
  } while (0)
#define STG_B(S, KH, KT) do {                                                \
    const uint16_t* _p = wS + (size_t)(KT) * 64 + (KH) * 32;                 \
    gload16(_p,                   &shmem[BOFF(S, KH) + (w * 32) * 32]);      \
    gload16(_p + (size_t)16 * K,  &shmem[BOFF(S, KH) + (w * 32 + 16) * 32]); \
  } while (0)
#define LDA(S, KH, MI) (*(const s16x8*)&shmem[AOFF(S, KH) + (wm * 128 + (MI) * 16 + fr) * 32 + pu])
#define LDB(S, KH, NJ) (*(const s16x8*)&shmem[BOFF(S, KH) + (wn * 64 + (NJ) * 16 + fr) * 32 + pu])
#define MFMA16(Q) do {                                                       \
    __builtin_amdgcn_s_setprio(1);                                           \
    _Pragma("unroll")                                                        \
    for (int mi = 0; mi < 8; ++mi)                                           \
      acc[mi][2*(Q)] = __builtin_amdgcn_mfma_f32_16x16x32_bf16(              \
          aF[mi], bF0, acc[mi][2*(Q)], 0, 0, 0);                             \
    _Pragma("unroll")                                                        \
    for (int mi = 0; mi < 8; ++mi)                                           \
      acc[mi][2*(Q)+1] = __builtin_amdgcn_mfma_f32_16x16x32_bf16(            \
          aF[mi], bF1, acc[mi][2*(Q)+1], 0, 0, 0);                           \
    __builtin_amdgcn_s_setprio(0);                                           \
  } while (0)

  STG_A(0, 0, 0); STG_B(0, 0, 0); STG_A(0, 1, 0); STG_B(0, 1, 0);
  STG_A(1, 0, 1); STG_B(1, 0, 1);
  VMCNT0();
  BARRIER();

  const int NI = K / 128;
  s16x8 aF[8], bF0, bF1;

  for (int i = 0; i < NI; ++i) {
    const bool nl = (i < NI - 1);
    const size_t t1 = 2 * i + 1, t2 = 2 * i + 2, t3 = 2 * i + 3;
#pragma unroll
    for (int mi = 0; mi < 8; ++mi) aF[mi] = LDA(0, 0, mi);
    bF0 = LDB(0, 0, 0); bF1 = LDB(0, 0, 1);
    STG_A(1, 1, t1);
    BARRIER(); WAITLGKM(); MFMA16(0); BARRIER();
    bF0 = LDB(0, 0, 2); bF1 = LDB(0, 0, 3);
    STG_B(1, 1, t1);
    BARRIER(); WAITLGKM(); MFMA16(1); BARRIER();
#pragma unroll
    for (int mi = 0; mi < 8; ++mi) aF[mi] = LDA(0, 1, mi);
    bF0 = LDB(0, 1, 0); bF1 = LDB(0, 1, 1);
    if (nl) STG_A(0, 0, t2);
    BARRIER(); WAITLGKM(); MFMA16(0); BARRIER();
    bF0 = LDB(0, 1, 2); bF1 = LDB(0, 1, 3);
    if (nl) STG_B(0, 0, t2);
    BARRIER(); WAITLGKM(); MFMA16(1);
    if (nl) VMCNT4(); else VMCNT0();
    BARRIER();
#pragma unroll
    for (int mi = 0; mi < 8; ++mi) aF[mi] = LDA(1, 0, mi);
    bF0 = LDB(1, 0, 0); bF1 = LDB(1, 0, 1);
    if (nl) STG_A(0, 1, t2);
    BARRIER(); WAITLGKM(); MFMA16(0); BARRIER();
    bF0 = LDB(1, 0, 2); bF1 = LDB(1, 0, 3);
    if (nl) STG_B(0, 1, t2);
    BARRIER(); WAITLGKM(); MFMA16(1); BARRIER();
#pragma unroll
    for (int mi = 0; mi < 8; ++mi) aF[mi] = LDA(1, 1, mi);
    bF0 = LDB(1, 1, 0); bF1 = LDB(1, 1, 1);
    if (nl) STG_A(1, 0, t3);
    BARRIER(); WAITLGKM(); MFMA16(0); BARRIER();
    bF0 = LDB(1, 1, 2); bF1 = LDB(1, 1, 3);
    if (nl) STG_B(1, 0, t3);
    BARRIER(); WAITLGKM(); MFMA16(1);
    VMCNT4();
    BARRIER();
  }
#undef STG_A
#undef STG_B
#undef LDA
#undef LDB
#undef MFMA16
#undef AOFF
#undef BOFF

  const int r0 = m0 + wm * 128 + (l >> 4) * 4;
  const int lr0 = wm * 128 + (l >> 4) * 4;       // block-local row base
  const bool doRope = OBF && (n0 < 2048);        // qk region

  if (doRope) {
    if (tid < 128)
      ((float*)&shmem[65536])[tid] =
          (float)exp((double)tid * -0.071955784156063938);  // 1e4^(-i/128)
#pragma unroll
    for (int mi = 0; mi < 8; ++mi)
#pragma unroll
      for (int nj = 0; nj < 4; ++nj)
#pragma unroll
        for (int p = 0; p < 4; ++p)
          shmem[(lr0 + mi * 16 + p) * 256 + wn * 64 + fr + nj * 16] =
              f2b(acc[mi][nj][p]);
    __syncthreads();
    const float* invt = (const float*)&shmem[65536];
    const bool isq = (n0 < 1024);
    uint16_t* Cb = (uint16_t*)Cout;              // region 0
#pragma unroll
    for (int mi = 0; mi < 8; ++mi)
#pragma unroll
      for (int nj = 0; nj < 4; ++nj)
#pragma unroll
        for (int p = 0; p < 4; ++p) {
          const int lrow = lr0 + mi * 16 + p;
          const int c = wn * 64 + fr + nj * 16;
          const int grow = m0 + lrow;
          const int n = grow & (Nn - 1);
          const int i2 = c & 127;
          float sn, cs;
          sincosf((float)n * invt[i2], &sn, &cs);
          const float lo = b2f(shmem[lrow * 256 + i2]);
          const float hi = b2f(shmem[lrow * 256 + i2 + 128]);
          float val = (c < 128) ? (lo * cs - hi * sn) : (hi * cs + lo * sn);
          if (isq) val *= 0.0625f;
          Cb[(size_t)grow * 2048 + (n0 & 2047) + c] = f2b(val);
        }
  } else {
#pragma unroll
    for (int mi = 0; mi < 8; ++mi)
#pragma unroll
      for (int nj = 0; nj < 4; ++nj)
#pragma unroll
        for (int p = 0; p < 4; ++p) {
          const int row = r0 + mi * 16 + p;
          if (OBF) {
            uint16_t* Cb = (uint16_t*)Cout + (size_t)(n0 >> 11) * 16777216;
            const int col = (n0 & 2047) + wn * 64 + fr + nj * 16;
            Cb[(size_t)row * 2048 + col] = f2b(acc[mi][nj][p]);
          } else {
            const int col = n0 + wn * 64 + fr + nj * 16;
            ((float*)Cout)[(size_t)row * 2048 + col] = acc[mi][nj][p];
          }
        }
  }
}

// ---------------------------------------------------------------------------
// v transpose: vt[bh][w][n] = v[b][n][h*DV + w].  64x64 LDS tiles.
// (Cannot merge with post_tv: tk/attn/wob writes overlay vb, which this
// kernel still reads.)
// ---------------------------------------------------------------------------
__global__ __launch_bounds__(256) void transpose_v(const uint16_t* __restrict__ v,
                                                   uint16_t* __restrict__ vt) {
  const int nt = blockIdx.x & 63;
  const int wt = (blockIdx.x >> 6) & 7;
  const int bh = blockIdx.x >> 9;
  const int b = bh >> 2, h = bh & 3;
  __shared__ uint16_t t[64][72];
  const int lr = threadIdx.x >> 2, lc = (threadIdx.x & 3) * 16;
  const uint16_t* src = v + ((size_t)(b * Nn + nt * 64 + lr)) * DM + h * DV + wt * 64 + lc;
  *(uint4*)&t[lr][lc]     = *(const uint4*)src;
  *(uint4*)&t[lr][lc + 8] = *(const uint4*)(src + 8);
  __syncthreads();
  uint16_t out[16];
#pragma unroll
  for (int e = 0; e < 16; ++e) out[e] = t[lc + e][lr];
  uint16_t* dst = vt + ((size_t)bh * 512 + wt * 64 + lr) * 4096 + nt * 64 + lc;
  *(uint4*)dst       = *(uint4*)&out[0];
  *(uint4*)(dst + 8) = *(uint4*)&out[8];
}

// ---------------------------------------------------------------------------
// MERGED post_tv (all gated only on transpose_v; disjoint writes):
//   blocks [0,2048):    conv Wo -> wob        (writes [84,92)MB, dead-vb)
//   blocks [2048,4096): transpose_k -> kt     (writes [64,80)MB, dead-vb)
//   blocks [4096,4608): attn_mfma -> attn     (writes [80,84)MB, dead-vb)
// Inner code byte-identical to the round-16 standalone kernels.
// ---------------------------------------------------------------------------
__global__ __launch_bounds__(256) void post_tv(const float* __restrict__ Wo,
                                               uint16_t* __restrict__ wob,
                                               const uint16_t* __restrict__ qk,
                                               uint16_t* __restrict__ kt,
                                               uint16_t* __restrict__ attn) {
  __shared__ uint16_t t[64][72];
  const int bid = blockIdx.x;
  if (bid < 2048) {
    conv_body(Wo, wob, bid * 256 + threadIdx.x, DM * DM / 8);
  } else if (bid < 4096) {
    const int bb = bid - 2048;
    const int nt = bb & 63;
    const int dt = (bb >> 6) & 3;
    const int bh = bb >> 8;
    const int b = bh >> 2, h = bh & 3;
    const int lr = threadIdx.x >> 2, lc = (threadIdx.x & 3) * 16;
    const uint16_t* src = qk + ((size_t)(b * Nn + nt * 64 + lr)) * QKS + 1024 + h * DK + dt * 64 + lc;
    *(uint4*)&t[lr][lc]     = *(const uint4*)src;
    *(uint4*)&t[lr][lc + 8] = *(const uint4*)(src + 8);
    __syncthreads();
    const float l2g = log2f(1.f - exp2f(-5.f - (float)h));
    uint16_t out[16];
#pragma unroll
    for (int e = 0; e < 16; ++e)
      out[e] = f2b(b2f(t[lc + e][lr]) * exp2f((float)(63 - (lc + e)) * l2g));
    uint16_t* dst = kt + ((size_t)bh * 256 + dt * 64 + lr) * 4096 + nt * 64 + lc;
    *(uint4*)dst       = *(uint4*)&out[0];
    *(uint4*)(dst + 8) = *(uint4*)&out[8];
  } else {
    const int bb = bid - 4096;
    const int c  = bb & 63;
    const int bh = bb >> 6;
    const int b = bh >> 2, h = bh & 3;
    const int tid = threadIdx.x;
    const int l = tid & 63, w = tid >> 6;
    const int fr = l & 15, fk = (l >> 4) * 8;
    const int n0 = c * CH;
    const uint16_t* qbase = qk + ((size_t)(b * Nn + n0)) * QKS + h * DK;
    const uint16_t* kbase = qbase + 1024;
    f32x4 acc[4];
#pragma unroll
    for (int nj = 0; nj < 4; ++nj) {
      f32x4 z = {0.f, 0.f, 0.f, 0.f};
      acc[nj] = z;
    }
#pragma unroll
    for (int ks = 0; ks < 8; ++ks) {
      s16x8 qf = *(const s16x8*)(qbase + (size_t)(w * 16 + fr) * QKS + ks * 32 + fk);
      s16x8 kf[4];
#pragma unroll
      for (int nj = 0; nj < 4; ++nj)
        kf[nj] = *(const s16x8*)(kbase + (size_t)(nj * 16 + fr) * QKS + ks * 32 + fk);
#pragma unroll
      for (int nj = 0; nj < 4; ++nj)
        acc[nj] = __builtin_amdgcn_mfma_f32_16x16x32_bf16(qf, kf[nj], acc[nj], 0, 0, 0);
    }
    const float l2g = log2f(1.f - exp2f(-5.f - (float)h));
    uint16_t* ab = attn + ((size_t)bh * 64 + c) * 4096;
    const int rbase = (l >> 4) * 4;
#pragma unroll
    for (int pp = 0; pp < 4; ++pp) {
      const int i = w * 16 + rbase + pp;
#pragma unroll
      for (int nj = 0; nj < 4; ++nj) {
        const int j = nj * 16 + fr;
        const float val = (i >= j) ? acc[nj][pp] * exp2f((float)(i - j) * l2g) : 0.f;
        ab[(size_t)i * 64 + j] = f2b(val);
      }
    }
  }
}

// ---------------------------------------------------------------------------
// Kernel A: U_c^T[w,d] = sum_j vt[w,j] * kt[d,j]. MERGED: grid 1024 covers
// two dv slices (p = pbase + blockIdx.x>>9, U half selected to match).
// ---------------------------------------------------------------------------
__global__ __launch_bounds__(256) void chunk_outer(const uint16_t* __restrict__ kt,
                                                   const uint16_t* __restrict__ vt,
                                                   uint16_t* __restrict__ U0,
                                                   uint16_t* __restrict__ U1,
                                                   int pbase) {
  const int sub = blockIdx.x >> 9;
  uint16_t* U = sub ? U1 : U0;
  const int p = pbase + sub;
  const int c  = blockIdx.x & 63;
  const int bh = (blockIdx.x >> 6) & 7;
  const int tid = threadIdx.x;
  const int l = tid & 63, w = tid >> 6;
  const int wrow = (w >> 1) * 64;     // w' base (M)
  const int wcol = (w & 1) * 128;     // d  base (N)
  const int fr = l & 15, fk = (l >> 4) * 8;
  const int n0 = c * CH;
  const uint16_t* vtb = vt + ((size_t)bh * 512 + p * 128) * 4096 + n0;
  const uint16_t* ktb = kt + ((size_t)bh * 256) * 4096 + n0;
  f32x4 acc[4][8];
#pragma unroll
  for (int mi = 0; mi < 4; ++mi)
#pragma unroll
    for (int nj = 0; nj < 8; ++nj) {
      f32x4 z = {0.f, 0.f, 0.f, 0.f};
      acc[mi][nj] = z;
    }
#pragma unroll
  for (int ks = 0; ks < 2; ++ks) {
    s16x8 af[4], bf8[8];
#pragma unroll
    for (int mi = 0; mi < 4; ++mi)
      af[mi] = *(const s16x8*)(vtb + (size_t)(wrow + mi * 16 + fr) * 4096 + ks * 32 + fk);
#pragma unroll
    for (int nj = 0; nj < 8; ++nj)
      bf8[nj] = *(const s16x8*)(ktb + (size_t)(wcol + nj * 16 + fr) * 4096 + ks * 32 + fk);
#pragma unroll
    for (int mi = 0; mi < 4; ++mi)
#pragma unroll
      for (int nj = 0; nj < 8; ++nj)
        acc[mi][nj] = __builtin_amdgcn_mfma_f32_16x16x32_bf16(af[mi], bf8[nj],
                                                              acc[mi][nj], 0, 0, 0);
  }
  uint16_t* Ub = U + (size_t)bh * 2097152 + (size_t)c * 32768;
  const int rbase = (l >> 4) * 4;
#pragma unroll
  for (int mi = 0; mi < 4; ++mi)
#pragma unroll
    for (int nj = 0; nj < 8; ++nj)
#pragma unroll
      for (int pp = 0; pp < 4; ++pp) {
        const int wq = wrow + mi * 16 + rbase + pp;
        const int d  = wcol + nj * 16 + fr;
        Ub[(size_t)wq * 256 + d] = f2b(acc[mi][nj][pp]);
      }
}

// ---------------------------------------------------------------------------
// Kernel B: in-place state scan. MERGED: grid 2048 covers both U halves.
// ---------------------------------------------------------------------------
__global__ __launch_bounds__(256) void state_scan(uint16_t* __restrict__ U0,
                                                  uint16_t* __restrict__ U1) {
  uint16_t* U = (blockIdx.x >= 1024) ? U1 : U0;
  const int gid = (blockIdx.x & 1023) * 256 + threadIdx.x;  // < 262144
  const int bh = gid >> 15;
  const int e  = gid & 32767;
  const int h  = bh & 3;
  const float l2g = log2f(1.f - exp2f(-5.f - (float)h));
  const float gC = exp2f(64.f * l2g);
  uint16_t* p = U + (size_t)bh * 2097152 + e;
  float S = 0.f;
  for (int cb = 0; cb < 8; ++cb) {
    uint16_t* base = p + (size_t)cb * 8 * 32768;
    float u[8];
#pragma unroll
    for (int ee = 0; ee < 8; ++ee) u[ee] = b2f(base[(size_t)ee * 32768]);
#pragma unroll
    for (int ee = 0; ee < 8; ++ee) {
      base[(size_t)ee * 32768] = f2b(S);
      S = gC * S + u[ee];
    }
  }
}

// ---------------------------------------------------------------------------
// Kernel C: o[i,w] = (attn_c @ v_c)[i,w] + gamma^(i+1)*(q_c @ S_c)[i,w]
// MERGED: grid 1024, same (p, U) selection as chunk_outer.
// ---------------------------------------------------------------------------
__global__ __launch_bounds__(256) void scan_out(const uint16_t* __restrict__ qk,
                                                const uint16_t* __restrict__ vt,
                                                const uint16_t* __restrict__ attn,
                                                const uint16_t* __restrict__ U0,
                                                const uint16_t* __restrict__ U1,
                                                uint16_t* __restrict__ o, int pbase) {
  const int sub = blockIdx.x >> 9;
  const uint16_t* U = sub ? U1 : U0;
  const int p = pbase + sub;
  const int c  = blockIdx.x & 63;
  const int bh = (blockIdx.x >> 6) & 7;
  const int b = bh >> 2, h = bh & 3;
  const int tid = threadIdx.x;
  const int l = tid & 63, wv = tid >> 6;
  const int wcol = wv * 32;                 // output col base (within pass 128)
  const int fr = l & 15, fk = (l >> 4) * 8;
  const int n0 = c * CH;
  f32x4 aQS[4][2], aPV[4][2];
#pragma unroll
  for (int mi = 0; mi < 4; ++mi)
#pragma unroll
    for (int nj = 0; nj < 2; ++nj) {
      f32x4 z = {0.f, 0.f, 0.f, 0.f};
      aQS[mi][nj] = z; aPV[mi][nj] = z;
    }
  const uint16_t* qbase = qk + ((size_t)(b * Nn + n0)) * QKS + h * DK;
  const uint16_t* Ub = U + (size_t)bh * 2097152 + (size_t)c * 32768;
  // q @ S  (K = 256)
#pragma unroll
  for (int ks = 0; ks < 8; ++ks) {
    s16x8 qf[4], sf[2];
#pragma unroll
    for (int mi = 0; mi < 4; ++mi)
      qf[mi] = *(const s16x8*)(qbase + (size_t)(mi * 16 + fr) * QKS + ks * 32 + fk);
#pragma unroll
    for (int nj = 0; nj < 2; ++nj)
      sf[nj] = *(const s16x8*)(Ub + (size_t)(wcol + nj * 16 + fr) * 256 + ks * 32 + fk);
#pragma unroll
    for (int mi = 0; mi < 4; ++mi)
#pragma unroll
      for (int nj = 0; nj < 2; ++nj)
        aQS[mi][nj] = __builtin_amdgcn_mfma_f32_16x16x32_bf16(qf[mi], sf[nj],
                                                              aQS[mi][nj], 0, 0, 0);
  }
  // attn @ v  (K = 64)
  const uint16_t* ab = attn + ((size_t)bh * 64 + c) * 4096;
  const uint16_t* vtb = vt + ((size_t)bh * 512 + p * 128) * 4096 + n0;
#pragma unroll
  for (int ks = 0; ks < 2; ++ks) {
    s16x8 af[4], vf[2];
#pragma unroll
    for (int mi = 0; mi < 4; ++mi)
      af[mi] = *(const s16x8*)(ab + (size_t)(mi * 16 + fr) * 64 + ks * 32 + fk);
#pragma unroll
    for (int nj = 0; nj < 2; ++nj)
      vf[nj] = *(const s16x8*)(vtb + (size_t)(wcol + nj * 16 + fr) * 4096 + ks * 32 + fk);
#pragma unroll
    for (int mi = 0; mi < 4; ++mi)
#pragma unroll
      for (int nj = 0; nj < 2; ++nj)
        aPV[mi][nj] = __builtin_amdgcn_mfma_f32_16x16x32_bf16(af[mi], vf[nj],
                                                              aPV[mi][nj], 0, 0, 0);
  }
  const float l2g = log2f(1.f - exp2f(-5.f - (float)h));
  const int rbase = (l >> 4) * 4;
#pragma unroll
  for (int mi = 0; mi < 4; ++mi)
#pragma unroll
    for (int pp = 0; pp < 4; ++pp) {
      const int i = mi * 16 + rbase + pp;
      const float gi = exp2f((float)(i + 1) * l2g);
#pragma unroll
      for (int nj = 0; nj < 2; ++nj) {
        const int wc_ = wcol + nj * 16 + fr;
        const float val = aPV[mi][nj][pp] + gi * aQS[mi][nj][pp];
        o[((size_t)(b * Nn + n0 + i)) * DM + h * DV + p * 128 + wc_] = f2b(val);
      }
    }
}

// ---------------------------------------------------------------------------
// GroupNorm over DV per (b,n,h) + SiLU gate (o bf16), in place into g.
// ---------------------------------------------------------------------------
__global__ __launch_bounds__(256) void gn_gate(const uint16_t* __restrict__ o,
                                               uint16_t* __restrict__ g,
                                               const float* __restrict__ gw) {
  const int bn = blockIdx.x;
  const int tid = threadIdx.x;
  const int h = tid >> 6;
  const int lane = tid & 63;
  const size_t base = (size_t)bn * DM + h * DV + lane * 8;
  uint4 ov4 = *(const uint4*)&o[base];
  float ov[8] = { b2f((uint16_t)ov4.x), b2f((uint16_t)(ov4.x >> 16)),
                  b2f((uint16_t)ov4.y), b2f((uint16_t)(ov4.y >> 16)),
                  b2f((uint16_t)ov4.z), b2f((uint16_t)(ov4.z >> 16)),
                  b2f((uint16_t)ov4.w), b2f((uint16_t)(ov4.w >> 16)) };
  float ss = 0.f;
#pragma unroll
  for (int e = 0; e < 8; ++e) ss += ov[e] * ov[e];
#pragma unroll
  for (int m = 1; m < 64; m <<= 1) ss += __shfl_xor(ss, m, 64);
  const float r = rsqrtf(ss * (1.f / 512.f) + 1e-5f);
  uint4 gv = *(const uint4*)&g[base];
  float gf[8] = { b2f((uint16_t)gv.x), b2f((uint16_t)(gv.x >> 16)),
                  b2f((uint16_t)gv.y), b2f((uint16_t)(gv.y >> 16)),
                  b2f((uint16_t)gv.z), b2f((uint16_t)(gv.z >> 16)),
                  b2f((uint16_t)gv.w), b2f((uint16_t)(gv.w >> 16)) };
  const float* gwp = gw + lane * 8;
  uint16_t res[8];
#pragma unroll
  for (int e = 0; e < 8; ++e) {
    float sil = gf[e] / (1.f + expf(-gf[e]));
    res[e] = f2b(ov[e] * r * gwp[e] * sil);
  }
  uint4 outv;
  outv.x = (uint32_t)res[0] | ((uint32_t)res[1] << 16);
  outv.y = (uint32_t)res[2] | ((uint32_t)res[3] << 16);
  outv.z = (uint32_t)res[4] | ((uint32_t)res[5] << 16);
  outv.w = (uint32_t)res[6] | ((uint32_t)res[7] << 16);
  *(uint4*)&g[base] = outv;
}

// ---------------------------------------------------------------------------
// ws layout (MB), peak 160 (proven size). Overlays, write-before-read ordered:
//   [  0, 32)  xb (dead after fused GEMM)            -> U0 (scan)
//   [ 32, 64)  qkb   [ 64, 96) vb -> kt[64,80) attn[80,84) wob[84,92)
//   [ 96,128)  gb
//   [128,152)  wall (dead after fused GEMM)          -> vt[128,160)
// d_out (64MB): o16 bf16 in [0,32); U1 scratch in [32,64) during the scan
// (fully written by chunk_outer before read; final GEMM overwrites ALL of
// d_out fp32). Every region fully written before read -> graph-replay safe.
// Dispatch count 15 -> 12 this round (conv_all, post_tv merges).
// ---------------------------------------------------------------------------
extern "C" void kernel_launch(void* const* d_in, const int* in_sizes, int n_in,
                              void* d_out, int out_size, void* d_ws, size_t ws_size,
                              hipStream_t stream) {
  const float* x  = (const float*)d_in[0];
  const float* Wq = (const float*)d_in[1];
  const float* Wk = (const float*)d_in[2];
  const float* Wv = (const float*)d_in[3];
  const float* Wg = (const float*)d_in[4];
  const float* Wo = (const float*)d_in[5];
  const float* gw = (const float*)d_in[6];

  char* base = (char*)d_ws;
  uint16_t* xb   = (uint16_t*)(base);                       // [0,32)
  uint16_t* U0   = (uint16_t*)(base);                       // overlays xb (scan)
  uint16_t* qkb  = (uint16_t*)(base + ((size_t)32 << 20));  // [32,64)
  uint16_t* vb   = (uint16_t*)(base + ((size_t)64 << 20));  // [64,96)
  uint16_t* kt   = (uint16_t*)(base + ((size_t)64 << 20));  // overlays vb
  uint16_t* attn = (uint16_t*)(base + ((size_t)80 << 20));  // overlays vb
  uint16_t* wob  = (uint16_t*)(base + ((size_t)84 << 20));  // overlays vb
  uint16_t* gb   = (uint16_t*)(base + ((size_t)96 << 20));  // [96,128)
  uint16_t* wall = (uint16_t*)(base + ((size_t)128 << 20)); // [128,152)
  uint16_t* vt   = (uint16_t*)(base + ((size_t)128 << 20)); // overlays wall
  uint16_t* qb   = qkb;                    // q = cols 0-1023
  uint16_t* o16  = (uint16_t*)d_out;       // bf16 o scratch (d_out [0,32MB))
  uint16_t* U1   = (uint16_t*)d_out + 16777216;  // d_out [32,64MB) scratch

  dim3 blk(256), blkG(512);
  // phase 1: ONE merged conversion + ONE fused GEMM (qk|v|g, rope in epilogue)
  conv_all<<<dim3(14336), blk, 0, stream>>>(x, Wq, Wk, Wv, Wg, xb, wall);
  gemm8p<true><<<dim3(M/256, 6144/256), blkG, 0, stream>>>(xb, wall, qkb, DM);
  // phase 2: transpose_v, then merged {conv Wo | transpose_k | attn_mfma}
  transpose_v<<<dim3(8*8*64), blk, 0, stream>>>(vb, vt);     // vb -> dead
  post_tv<<<dim3(4608), blk, 0, stream>>>(Wo, wob, qkb, kt, attn);
  // scan: 2 super-passes of 256 dv cols; U0 overlays dead xb, U1 in d_out.
  for (int s = 0; s < 2; ++s) {
    chunk_outer<<<dim3(1024), blk, 0, stream>>>(kt, vt, U0, U1, 2 * s);
    state_scan<<<dim3(2048),  blk, 0, stream>>>(U0, U1);
    scan_out<<<dim3(1024),    blk, 0, stream>>>(qb, vt, attn, U0, U1, o16, 2 * s);
  }
  // epilogue
  gn_gate<<<dim3(M), blk, 0, stream>>>(o16, gb, gw);
  gemm8p<false><<<dim3(M/256, DM/256), blkG, 0, stream>>>(gb, wob, (float*)d_out, DM);
}